// Round 1
// baseline (4979.774 us; speedup 1.0000x reference)
//
#include <hip/hip_runtime.h>
#include <hip/hip_bf16.h>
#include <math.h>

// Shapes (fixed): B=32, C=3, H=128, W=128, HID=64, NP=64, P=16, E=768, NH=4, dh=192
// All inputs fp32. Output = concat(patches (32*64*3*16*16), translate (32*64*2)).

#define PI_F 3.14159265358979323846f

// ---------------- conv1: (32,3,128,128) -> (32,64,128,128), 3x3 SAME, ReLU ----------------
__global__ __launch_bounds__(256) void conv3x3_relu_c3(
    const float* __restrict__ x, const float* __restrict__ w,
    const float* __restrict__ bias, float* __restrict__ out) {
  int tid = threadIdx.x;
  int pix = blockIdx.x * 256 + tid;          // 0..16383
  int oc = blockIdx.y, b = blockIdx.z;
  int y = pix >> 7, xx = pix & 127;
  const float* wp = w + oc * 27;
  const float* xb = x + (size_t)b * 3 * 16384;
  float acc = bias[oc];
  #pragma unroll
  for (int ic = 0; ic < 3; ++ic) {
    #pragma unroll
    for (int ky = 0; ky < 3; ++ky) {
      int yy = y + ky - 1;
      if ((unsigned)yy < 128u) {
        const float* xr = xb + ic * 16384 + yy * 128;
        #pragma unroll
        for (int kx = 0; kx < 3; ++kx) {
          int xc = xx + kx - 1;
          if ((unsigned)xc < 128u) acc += wp[ic * 9 + ky * 3 + kx] * xr[xc];
        }
      }
    }
  }
  out[((size_t)(b * 64 + oc)) * 16384 + pix] = fmaxf(acc, 0.f);
}

// ---------------- conv2: (32,64,64,64) -> (32,64,64,64), 3x3 SAME, ReLU ----------------
__global__ __launch_bounds__(256) void conv3x3_relu_c64(
    const float* __restrict__ x, const float* __restrict__ w,
    const float* __restrict__ bias, float* __restrict__ out) {
  __shared__ float wsm[576];
  int tid = threadIdx.x;
  int oc = blockIdx.y, b = blockIdx.z;
  for (int i = tid; i < 576; i += 256) wsm[i] = w[oc * 576 + i];
  __syncthreads();
  int pix = blockIdx.x * 256 + tid;          // 0..4095
  int y = pix >> 6, xx = pix & 63;
  const float* xb = x + (size_t)b * 64 * 4096;
  float acc = bias[oc];
  for (int ic = 0; ic < 64; ++ic) {
    const float* xc = xb + ic * 4096;
    const float* wc = wsm + ic * 9;
    #pragma unroll
    for (int ky = 0; ky < 3; ++ky) {
      int yy = y + ky - 1;
      if ((unsigned)yy < 64u) {
        const float* xr = xc + yy * 64;
        #pragma unroll
        for (int kx = 0; kx < 3; ++kx) {
          int xc2 = xx + kx - 1;
          if ((unsigned)xc2 < 64u) acc += wc[ky * 3 + kx] * xr[xc2];
        }
      }
    }
  }
  out[((size_t)(b * 64 + oc)) * 4096 + pix] = fmaxf(acc, 0.f);
}

// ---------------- generic fp32 NT GEMM: C[M,N] = A[M,K] * Bw[N,K]^T + bias, opt ReLU ------
// Block: 256 threads = 16x16, each computes 4x4; tile 64x64, K-step 16.
// Requires M%64==0, N%64==0, K%16==0 (true for every call here).
template <int DO_RELU>
__global__ __launch_bounds__(256) void gemm_nt(
    const float* __restrict__ A, const float* __restrict__ Bw,
    const float* __restrict__ bias, float* __restrict__ C,
    int M, int N, int K) {
  __shared__ float As[16][68];   // [k][m], 68 => float4-aligned rows, padded
  __shared__ float Bs[16][68];   // [k][n]
  const int tid = threadIdx.x;
  const int tx = tid & 15, ty = tid >> 4;
  const int bm = blockIdx.y << 6, bn = blockIdx.x << 6;
  const int lrow = tid >> 2;           // 0..63
  const int lk = (tid & 3) << 2;       // 0,4,8,12
  const float* Ap = A + (size_t)(bm + lrow) * K + lk;
  const float* Bp = Bw + (size_t)(bn + lrow) * K + lk;
  float acc[4][4] = {};
  for (int kt = 0; kt < K; kt += 16) {
    float4 av = *(const float4*)(Ap + kt);
    float4 bv = *(const float4*)(Bp + kt);
    As[lk + 0][lrow] = av.x; As[lk + 1][lrow] = av.y;
    As[lk + 2][lrow] = av.z; As[lk + 3][lrow] = av.w;
    Bs[lk + 0][lrow] = bv.x; Bs[lk + 1][lrow] = bv.y;
    Bs[lk + 2][lrow] = bv.z; Bs[lk + 3][lrow] = bv.w;
    __syncthreads();
    #pragma unroll
    for (int kk = 0; kk < 16; ++kk) {
      float4 a = *(const float4*)&As[kk][ty << 2];
      float4 b = *(const float4*)&Bs[kk][tx << 2];
      acc[0][0] += a.x * b.x; acc[0][1] += a.x * b.y; acc[0][2] += a.x * b.z; acc[0][3] += a.x * b.w;
      acc[1][0] += a.y * b.x; acc[1][1] += a.y * b.y; acc[1][2] += a.y * b.z; acc[1][3] += a.y * b.w;
      acc[2][0] += a.z * b.x; acc[2][1] += a.z * b.y; acc[2][2] += a.z * b.z; acc[2][3] += a.z * b.w;
      acc[3][0] += a.w * b.x; acc[3][1] += a.w * b.y; acc[3][2] += a.w * b.z; acc[3][3] += a.w * b.w;
    }
    __syncthreads();
  }
  #pragma unroll
  for (int i = 0; i < 4; ++i) {
    int row = bm + (ty << 2) + i;
    #pragma unroll
    for (int j = 0; j < 4; ++j) {
      int col = bn + (tx << 2) + j;
      float v = acc[i][j] + bias[col];
      if (DO_RELU) v = fmaxf(v, 0.f);
      C[(size_t)row * N + col] = v;
    }
  }
}

// ---------------- attention: scores + softmax. one wave per (b,h,tq) ----------------
// qkv layout: [b*64+t][2304] with q at 0, k at 768, v at 1536; head h slice h*192..
__global__ __launch_bounds__(64) void attn_scores(
    const float* __restrict__ qkv, float* __restrict__ p, float scale) {
  int tq = blockIdx.x, h = blockIdx.y, b = blockIdx.z;
  int lane = threadIdx.x;                    // = tk
  __shared__ float qrow[192];
  const float* qp = qkv + ((size_t)(b * 64 + tq)) * 2304 + h * 192;
  for (int d = lane; d < 192; d += 64) qrow[d] = qp[d];
  __syncthreads();
  const float* kp = qkv + ((size_t)(b * 64 + lane)) * 2304 + 768 + h * 192;
  float s = 0.f;
  for (int d = 0; d < 192; ++d) s += qrow[d] * kp[d];
  s *= scale;
  float m = s;
  for (int off = 32; off; off >>= 1) m = fmaxf(m, __shfl_xor(m, off));
  float e = expf(s - m);
  float sum = e;
  for (int off = 32; off; off >>= 1) sum += __shfl_xor(sum, off);
  p[(((size_t)b * 4 + h) * 64 + tq) * 64 + lane] = e / sum;
}

// ---------------- attention: o = p @ v, output already in (b, t, e) layout --------------
__global__ __launch_bounds__(256) void attn_o(
    const float* __restrict__ p, const float* __restrict__ qkv, float* __restrict__ o) {
  size_t tid = (size_t)blockIdx.x * 256 + threadIdx.x;   // over 32*64*768
  if (tid >= (size_t)32 * 64 * 768) return;
  int e = (int)(tid % 768);
  int tq = (int)((tid / 768) % 64);
  int b = (int)(tid / (768 * 64));
  int h = e / 192;
  const float* pp = p + (((size_t)b * 4 + h) * 64 + tq) * 64;
  const float* vp = qkv + (size_t)b * 64 * 2304 + 1536 + e;
  float acc = 0.f;
  for (int tk = 0; tk < 64; ++tk) acc += pp[tk] * vp[(size_t)tk * 2304];
  o[tid] = acc;
}

// ---------------- maxpool 2x2 stride 2: (32,64,128,128) -> (32,64,64,64) ----------------
__global__ __launch_bounds__(256) void maxpool2k(
    const float* __restrict__ x, float* __restrict__ out) {
  size_t tid = (size_t)blockIdx.x * 256 + threadIdx.x;
  if (tid >= (size_t)32 * 64 * 64 * 64) return;
  int xx = (int)(tid & 63);
  int y = (int)((tid >> 6) & 63);
  size_t plane = tid >> 12;
  const float* xp = x + plane * 16384 + (size_t)y * 2 * 128 + xx * 2;
  out[tid] = fmaxf(fmaxf(xp[0], xp[1]), fmaxf(xp[128], xp[129]));
}

// ---------------- tiny-N GEMM (fc2: N=4) ----------------
__global__ __launch_bounds__(256) void gemm_small_n(
    const float* __restrict__ A, const float* __restrict__ Bw,
    const float* __restrict__ bias, float* __restrict__ C,
    int M, int N, int K) {
  int tid = blockIdx.x * 256 + threadIdx.x;
  if (tid >= M * N) return;
  int n = tid % N, m = tid / N;
  const float* a = A + (size_t)m * K;
  const float* bb = Bw + (size_t)n * K;
  float acc = bias[n];
  for (int k = 0; k < K; ++k) acc += a[k] * bb[k];
  C[tid] = acc;
}

// ---------------- transform params + translate output ----------------
__global__ __launch_bounds__(64) void params_k(
    const float* __restrict__ tp, float* __restrict__ par, float* __restrict__ trans_out) {
  int m = blockIdx.x * 64 + threadIdx.x;   // 0..2047  (b*64+np)
  if (m >= 2048) return;
  float t0 = tp[m * 4 + 0], t1 = tp[m * 4 + 1], t2 = tp[m * 4 + 2], t3 = tp[m * 4 + 3];
  float trx = tanhf(t0), tryy = tanhf(t1);
  float s = (1.f / (1.f + expf(-t2))) * 0.3f;          // sx == sy
  float rot = tanhf(t3) * PI_F;
  float c = cosf(rot), sn = sinf(rot);
  float x_ext = fminf(s * fabsf(c) + s * fabsf(sn), 1.f);
  float y_ext = fminf(s * fabsf(sn) + s * fabsf(c), 1.f);
  float tx = trx * (1.f - x_ext);
  float ty = tryy * (1.f - y_ext);
  par[m * 8 + 0] = s * c;      // ta
  par[m * 8 + 1] = -s * sn;    // tb
  par[m * 8 + 2] = s * sn;     // tc
  par[m * 8 + 3] = s * c;      // td
  par[m * 8 + 4] = tx;
  par[m * 8 + 5] = ty;
  trans_out[m * 2 + 0] = tx;
  trans_out[m * 2 + 1] = ty;
}

// ---------------- bilinear grid sample: out (32*64, 3, 16, 16) ----------------
__global__ __launch_bounds__(256) void sample_k(
    const float* __restrict__ x, const float* __restrict__ par, float* __restrict__ out) {
  int tid = blockIdx.x * 256 + threadIdx.x;   // over 32*64*3*256
  if (tid >= 32 * 64 * 3 * 256) return;
  int pj = tid & 15, pi = (tid >> 4) & 15;
  int c = (tid >> 8) % 3;
  int bp = tid / 768;                 // b*64+np
  int b = bp >> 6;
  const float* pp = par + bp * 8;
  float ta = pp[0], tb = pp[1], tc = pp[2], td = pp[3], tx = pp[4], ty = pp[5];
  float bj = (2.f * pj + 1.f) / 16.f - 1.f;
  float bi = (2.f * pi + 1.f) / 16.f - 1.f;
  float gx = ta * bj + tb * bi + tx;
  float gy = tc * bj + td * bi + ty;
  float xs = ((gx + 1.f) * 128.f - 1.f) * 0.5f;
  float ys = ((gy + 1.f) * 128.f - 1.f) * 0.5f;
  float x0f = floorf(xs), y0f = floorf(ys);
  float wx = xs - x0f, wy = ys - y0f;
  int x0 = (int)x0f, y0 = (int)y0f, x1 = x0 + 1, y1 = y0 + 1;
  const float* img = x + ((size_t)b * 3 + c) * 16384;
  auto g = [&](int yi, int xi) -> float {
    bool v = (xi >= 0) && (xi < 128) && (yi >= 0) && (yi < 128);
    int yc = yi < 0 ? 0 : (yi > 127 ? 127 : yi);
    int xc = xi < 0 ? 0 : (xi > 127 ? 127 : xi);
    float val = img[yc * 128 + xc];
    return v ? val : 0.f;
  };
  float v00 = g(y0, x0), v01 = g(y0, x1), v10 = g(y1, x0), v11 = g(y1, x1);
  out[tid] = v00 * (1.f - wx) * (1.f - wy) + v01 * wx * (1.f - wy) +
             v10 * (1.f - wx) * wy + v11 * wx * wy;
}

extern "C" void kernel_launch(void* const* d_in, const int* in_sizes, int n_in,
                              void* d_out, int out_size, void* d_ws, size_t ws_size,
                              hipStream_t stream) {
  const float* x        = (const float*)d_in[0];
  const float* conv1_w  = (const float*)d_in[1];
  const float* conv1_b  = (const float*)d_in[2];
  const float* a1_in_w  = (const float*)d_in[3];
  const float* a1_in_b  = (const float*)d_in[4];
  const float* a1_qkv_w = (const float*)d_in[5];
  const float* a1_qkv_b = (const float*)d_in[6];
  const float* a1_out_w = (const float*)d_in[7];
  const float* a1_out_b = (const float*)d_in[8];
  const float* a1_proj_w = (const float*)d_in[9];
  const float* a1_proj_b = (const float*)d_in[10];
  const float* conv2_w  = (const float*)d_in[11];
  const float* conv2_b  = (const float*)d_in[12];
  const float* a2_in_w  = (const float*)d_in[13];
  const float* a2_in_b  = (const float*)d_in[14];
  const float* a2_qkv_w = (const float*)d_in[15];
  const float* a2_qkv_b = (const float*)d_in[16];
  const float* a2_out_w = (const float*)d_in[17];
  const float* a2_out_b = (const float*)d_in[18];
  const float* a2_proj_w = (const float*)d_in[19];
  const float* a2_proj_b = (const float*)d_in[20];
  const float* fc1_w    = (const float*)d_in[21];
  const float* fc1_b    = (const float*)d_in[22];
  const float* fc2_w    = (const float*)d_in[23];
  const float* fc2_b    = (const float*)d_in[24];
  float* out = (float*)d_out;

  // Workspace layout (bytes). Peak ~198 MiB with reuse.
  char* ws = (char*)d_ws;
  float* f1  = (float*)(ws + 0);            // 134,217,728 B  (32,64,128,128); later reused
  float* y1  = f1;                          // proj1 output overwrites f1 (f1 dead by then)
  float* f2  = (float*)(ws + 134217728);    // 33,554,432 B   (32,64,64,64) pool out
  float* y2  = f2;                          // proj2 output overwrites f2 (f2 dead by then)
  float* f3  = (float*)(ws + 0);            // 33,554,432 B   conv2 out (f1 region, dead)
  float* h1  = (float*)(ws + 67108864);     // 16,777,216 B   fc1 out (f1 region, disjoint from f3)
  float* t   = (float*)(ws + 167772160);    // 6,291,456 B    (2048,768)
  float* qkv = (float*)(ws + 174063616);    // 18,874,368 B   (2048,2304)
  float* p   = (float*)(ws + 192937984);    // 2,097,152 B    (32,4,64,64)
  float* o   = (float*)(ws + 195035136);    // 6,291,456 B    (2048,768)
  float* ao  = (float*)(ws + 201326592);    // 6,291,456 B    (2048,768)
  float* tp  = (float*)(ws + 207618048);    // 32,768 B       (2048,4)
  float* par = (float*)(ws + 207650816);    // 65,536 B       (2048,8)

  const float scale = 0.07216878364870323f; // 1/sqrt(192)

  // Stage 1: conv1 + relu
  conv3x3_relu_c3<<<dim3(64, 64, 32), 256, 0, stream>>>(x, conv1_w, conv1_b, f1);
  // attn1: t = f1(2048,16384) @ a1_in_w^T
  gemm_nt<0><<<dim3(12, 32), 256, 0, stream>>>(f1, a1_in_w, a1_in_b, t, 2048, 768, 16384);
  gemm_nt<0><<<dim3(36, 32), 256, 0, stream>>>(t, a1_qkv_w, a1_qkv_b, qkv, 2048, 2304, 768);
  attn_scores<<<dim3(64, 4, 32), 64, 0, stream>>>(qkv, p, scale);
  attn_o<<<6144, 256, 0, stream>>>(p, qkv, o);
  gemm_nt<0><<<dim3(12, 32), 256, 0, stream>>>(o, a1_out_w, a1_out_b, ao, 2048, 768, 768);
  gemm_nt<0><<<dim3(256, 32), 256, 0, stream>>>(ao, a1_proj_w, a1_proj_b, y1, 2048, 16384, 768);
  // pool
  maxpool2k<<<32768, 256, 0, stream>>>(y1, f2);
  // conv2 + relu
  conv3x3_relu_c64<<<dim3(16, 64, 32), 256, 0, stream>>>(f2, conv2_w, conv2_b, f3);
  // attn2
  gemm_nt<0><<<dim3(12, 32), 256, 0, stream>>>(f3, a2_in_w, a2_in_b, t, 2048, 768, 4096);
  gemm_nt<0><<<dim3(36, 32), 256, 0, stream>>>(t, a2_qkv_w, a2_qkv_b, qkv, 2048, 2304, 768);
  attn_scores<<<dim3(64, 4, 32), 64, 0, stream>>>(qkv, p, scale);
  attn_o<<<6144, 256, 0, stream>>>(p, qkv, o);
  gemm_nt<0><<<dim3(12, 32), 256, 0, stream>>>(o, a2_out_w, a2_out_b, ao, 2048, 768, 768);
  gemm_nt<0><<<dim3(64, 32), 256, 0, stream>>>(ao, a2_proj_w, a2_proj_b, y2, 2048, 4096, 768);
  // head
  gemm_nt<1><<<dim3(32, 32), 256, 0, stream>>>(y2, fc1_w, fc1_b, h1, 2048, 2048, 4096);
  gemm_small_n<<<32, 256, 0, stream>>>(h1, fc2_w, fc2_b, tp, 2048, 4, 2048);
  params_k<<<32, 64, 0, stream>>>(tp, par, out + 1572864);
  sample_k<<<6144, 256, 0, stream>>>(x, par, out);
}

// Round 2
// 3824.314 us; speedup vs baseline: 1.3021x; 1.3021x over previous
//
#include <hip/hip_runtime.h>
#include <hip/hip_bf16.h>
#include <math.h>

// Shapes (fixed): B=32, C=3, H=128, W=128, HID=64, NP=64, P=16, E=768, NH=4, dh=192
// All inputs fp32. Output = concat(patches (32*64*3*16*16), translate (32*64*2)).

#define PI_F 3.14159265358979323846f

// ---------------- conv1: (32,3,128,128) -> (32,64,128,128), 3x3 SAME, ReLU ----------------
__global__ __launch_bounds__(256) void conv3x3_relu_c3(
    const float* __restrict__ x, const float* __restrict__ w,
    const float* __restrict__ bias, float* __restrict__ out) {
  int tid = threadIdx.x;
  int pix = blockIdx.x * 256 + tid;          // 0..16383
  int oc = blockIdx.y, b = blockIdx.z;
  int y = pix >> 7, xx = pix & 127;
  const float* wp = w + oc * 27;
  const float* xb = x + (size_t)b * 3 * 16384;
  float acc = bias[oc];
  #pragma unroll
  for (int ic = 0; ic < 3; ++ic) {
    #pragma unroll
    for (int ky = 0; ky < 3; ++ky) {
      int yy = y + ky - 1;
      if ((unsigned)yy < 128u) {
        const float* xr = xb + ic * 16384 + yy * 128;
        #pragma unroll
        for (int kx = 0; kx < 3; ++kx) {
          int xc = xx + kx - 1;
          if ((unsigned)xc < 128u) acc += wp[ic * 9 + ky * 3 + kx] * xr[xc];
        }
      }
    }
  }
  out[((size_t)(b * 64 + oc)) * 16384 + pix] = fmaxf(acc, 0.f);
}

// ---------------- conv2 (fast): (32,64,64,64) -> (32,64,64,64), 3x3 SAME, ReLU ------------
// Block: 256 threads -> 4 output rows x 64 cols x all 64 oc, one batch.
// Thread: 8 consecutive x-pixels x 8 ocs (64 accumulators).
// LDS: input chunk [8 ic][6 rows][68 cols] + weights [8 ic][9 k][64 oc] = 31.4 KB.
#define ICB 8
__global__ __launch_bounds__(256) void conv3x3_relu_c64_fast(
    const float* __restrict__ x, const float* __restrict__ w,
    const float* __restrict__ bias, float* __restrict__ out) {
  __shared__ float xs[ICB][6][68];   // img col c stored at index c+1; stride 68 breaks bank degeneracy
  __shared__ float wsm[ICB][9][64];  // [ic][k][oc]
  const int tid = threadIdx.x;
  const int b = blockIdx.y;
  const int y0 = blockIdx.x * 4;
  const int xg = (tid & 7) * 8;       // x base (0..56), float4-aligned in LDS
  const int row = (tid >> 3) & 3;     // output row within tile
  const int oc0 = (tid >> 5) * 8;     // 0..56
  const float* xb = x + (size_t)b * 64 * 4096;
  float acc[8][8] = {};               // [oc][px]
  for (int ic0 = 0; ic0 < 64; ic0 += ICB) {
    // stage input tile (zeros at borders)
    for (int i = tid; i < ICB * 6 * 68; i += 256) {
      int c = i % 68;
      int r = (i / 68) % 6;
      int ic = i / (68 * 6);
      int gy = y0 + r - 1;
      int gx = c - 1;
      float v = 0.f;
      if ((unsigned)gy < 64u && (unsigned)gx < 64u)
        v = xb[(size_t)(ic0 + ic) * 4096 + gy * 64 + gx];
      xs[ic][r][c] = v;
    }
    // stage weights: wsm[ic][k][oc] = w[oc][ic0+ic][k]
    for (int i = tid; i < ICB * 9 * 64; i += 256) {
      int oc = i & 63;
      int k = (i >> 6) % 9;
      int ic = i / (64 * 9);
      wsm[ic][k][oc] = w[(size_t)oc * 576 + (ic0 + ic) * 9 + k];
    }
    __syncthreads();
    #pragma unroll
    for (int ic = 0; ic < ICB; ++ic) {
      #pragma unroll
      for (int ky = 0; ky < 3; ++ky) {
        const float* rp = &xs[ic][row + ky][xg];   // stored cols xg..xg+11 = img cols xg-1..xg+10
        float4 r0 = *(const float4*)(rp);
        float4 r1 = *(const float4*)(rp + 4);
        float4 r2 = *(const float4*)(rp + 8);
        float v[10] = {r0.x, r0.y, r0.z, r0.w, r1.x, r1.y, r1.z, r1.w, r2.x, r2.y};
        #pragma unroll
        for (int kx = 0; kx < 3; ++kx) {
          const float* wr = &wsm[ic][ky * 3 + kx][oc0];
          float4 w0 = *(const float4*)(wr);
          float4 w1 = *(const float4*)(wr + 4);
          float wv[8] = {w0.x, w0.y, w0.z, w0.w, w1.x, w1.y, w1.z, w1.w};
          #pragma unroll
          for (int o = 0; o < 8; ++o)
            #pragma unroll
            for (int p = 0; p < 8; ++p)
              acc[o][p] += wv[o] * v[p + kx];
        }
      }
    }
    __syncthreads();
  }
  #pragma unroll
  for (int o = 0; o < 8; ++o) {
    float bo = bias[oc0 + o];
    float* op = out + ((size_t)(b * 64 + oc0 + o)) * 4096 + (y0 + row) * 64 + xg;
    #pragma unroll
    for (int p = 0; p < 8; ++p) op[p] = fmaxf(acc[o][p] + bo, 0.f);
  }
}

// ---------------- generic fp32 NT GEMM: C[M,N] = A[M,K] * Bw[N,K]^T + bias, opt ReLU ------
template <int DO_RELU>
__global__ __launch_bounds__(256) void gemm_nt(
    const float* __restrict__ A, const float* __restrict__ Bw,
    const float* __restrict__ bias, float* __restrict__ C,
    int M, int N, int K) {
  __shared__ float As[16][68];
  __shared__ float Bs[16][68];
  const int tid = threadIdx.x;
  const int tx = tid & 15, ty = tid >> 4;
  const int bm = blockIdx.y << 6, bn = blockIdx.x << 6;
  const int lrow = tid >> 2;
  const int lk = (tid & 3) << 2;
  const float* Ap = A + (size_t)(bm + lrow) * K + lk;
  const float* Bp = Bw + (size_t)(bn + lrow) * K + lk;
  float acc[4][4] = {};
  for (int kt = 0; kt < K; kt += 16) {
    float4 av = *(const float4*)(Ap + kt);
    float4 bv = *(const float4*)(Bp + kt);
    As[lk + 0][lrow] = av.x; As[lk + 1][lrow] = av.y;
    As[lk + 2][lrow] = av.z; As[lk + 3][lrow] = av.w;
    Bs[lk + 0][lrow] = bv.x; Bs[lk + 1][lrow] = bv.y;
    Bs[lk + 2][lrow] = bv.z; Bs[lk + 3][lrow] = bv.w;
    __syncthreads();
    #pragma unroll
    for (int kk = 0; kk < 16; ++kk) {
      float4 a = *(const float4*)&As[kk][ty << 2];
      float4 b = *(const float4*)&Bs[kk][tx << 2];
      acc[0][0] += a.x * b.x; acc[0][1] += a.x * b.y; acc[0][2] += a.x * b.z; acc[0][3] += a.x * b.w;
      acc[1][0] += a.y * b.x; acc[1][1] += a.y * b.y; acc[1][2] += a.y * b.z; acc[1][3] += a.y * b.w;
      acc[2][0] += a.z * b.x; acc[2][1] += a.z * b.y; acc[2][2] += a.z * b.z; acc[2][3] += a.z * b.w;
      acc[3][0] += a.w * b.x; acc[3][1] += a.w * b.y; acc[3][2] += a.w * b.z; acc[3][3] += a.w * b.w;
    }
    __syncthreads();
  }
  #pragma unroll
  for (int i = 0; i < 4; ++i) {
    int row = bm + (ty << 2) + i;
    #pragma unroll
    for (int j = 0; j < 4; ++j) {
      int col = bn + (tx << 2) + j;
      float v = acc[i][j] + bias[col];
      if (DO_RELU) v = fmaxf(v, 0.f);
      C[(size_t)row * N + col] = v;
    }
  }
}

// ---------------- attention: scores + softmax. one wave per (b,h,tq) ----------------
__global__ __launch_bounds__(64) void attn_scores(
    const float* __restrict__ qkv, float* __restrict__ p, float scale) {
  int tq = blockIdx.x, h = blockIdx.y, b = blockIdx.z;
  int lane = threadIdx.x;
  __shared__ float qrow[192];
  const float* qp = qkv + ((size_t)(b * 64 + tq)) * 2304 + h * 192;
  for (int d = lane; d < 192; d += 64) qrow[d] = qp[d];
  __syncthreads();
  const float* kp = qkv + ((size_t)(b * 64 + lane)) * 2304 + 768 + h * 192;
  float s = 0.f;
  for (int d = 0; d < 192; ++d) s += qrow[d] * kp[d];
  s *= scale;
  float m = s;
  for (int off = 32; off; off >>= 1) m = fmaxf(m, __shfl_xor(m, off));
  float e = expf(s - m);
  float sum = e;
  for (int off = 32; off; off >>= 1) sum += __shfl_xor(sum, off);
  p[(((size_t)b * 4 + h) * 64 + tq) * 64 + lane] = e / sum;
}

// ---------------- attention: o = p @ v ----------------
__global__ __launch_bounds__(256) void attn_o(
    const float* __restrict__ p, const float* __restrict__ qkv, float* __restrict__ o) {
  size_t tid = (size_t)blockIdx.x * 256 + threadIdx.x;
  if (tid >= (size_t)32 * 64 * 768) return;
  int e = (int)(tid % 768);
  int tq = (int)((tid / 768) % 64);
  int b = (int)(tid / (768 * 64));
  int h = e / 192;
  const float* pp = p + (((size_t)b * 4 + h) * 64 + tq) * 64;
  const float* vp = qkv + (size_t)b * 64 * 2304 + 1536 + e;
  float acc = 0.f;
  for (int tk = 0; tk < 64; ++tk) acc += pp[tk] * vp[(size_t)tk * 2304];
  o[tid] = acc;
}

// ---------------- maxpool 2x2 stride 2 ----------------
__global__ __launch_bounds__(256) void maxpool2k(
    const float* __restrict__ x, float* __restrict__ out) {
  size_t tid = (size_t)blockIdx.x * 256 + threadIdx.x;
  if (tid >= (size_t)32 * 64 * 64 * 64) return;
  int xx = (int)(tid & 63);
  int y = (int)((tid >> 6) & 63);
  size_t plane = tid >> 12;
  const float* xp = x + plane * 16384 + (size_t)y * 2 * 128 + xx * 2;
  out[tid] = fmaxf(fmaxf(xp[0], xp[1]), fmaxf(xp[128], xp[129]));
}

// ---------------- tiny-N GEMM (fc2: N=4) ----------------
__global__ __launch_bounds__(256) void gemm_small_n(
    const float* __restrict__ A, const float* __restrict__ Bw,
    const float* __restrict__ bias, float* __restrict__ C,
    int M, int N, int K) {
  int tid = blockIdx.x * 256 + threadIdx.x;
  if (tid >= M * N) return;
  int n = tid % N, m = tid / N;
  const float* a = A + (size_t)m * K;
  const float* bb = Bw + (size_t)n * K;
  float acc = bias[n];
  for (int k = 0; k < K; ++k) acc += a[k] * bb[k];
  C[tid] = acc;
}

// ---------------- transform params + translate output ----------------
__global__ __launch_bounds__(64) void params_k(
    const float* __restrict__ tp, float* __restrict__ par, float* __restrict__ trans_out) {
  int m = blockIdx.x * 64 + threadIdx.x;
  if (m >= 2048) return;
  float t0 = tp[m * 4 + 0], t1 = tp[m * 4 + 1], t2 = tp[m * 4 + 2], t3 = tp[m * 4 + 3];
  float trx = tanhf(t0), tryy = tanhf(t1);
  float s = (1.f / (1.f + expf(-t2))) * 0.3f;
  float rot = tanhf(t3) * PI_F;
  float c = cosf(rot), sn = sinf(rot);
  float x_ext = fminf(s * fabsf(c) + s * fabsf(sn), 1.f);
  float y_ext = fminf(s * fabsf(sn) + s * fabsf(c), 1.f);
  float tx = trx * (1.f - x_ext);
  float ty = tryy * (1.f - y_ext);
  par[m * 8 + 0] = s * c;
  par[m * 8 + 1] = -s * sn;
  par[m * 8 + 2] = s * sn;
  par[m * 8 + 3] = s * c;
  par[m * 8 + 4] = tx;
  par[m * 8 + 5] = ty;
  trans_out[m * 2 + 0] = tx;
  trans_out[m * 2 + 1] = ty;
}

// ---------------- bilinear grid sample ----------------
__global__ __launch_bounds__(256) void sample_k(
    const float* __restrict__ x, const float* __restrict__ par, float* __restrict__ out) {
  int tid = blockIdx.x * 256 + threadIdx.x;
  if (tid >= 32 * 64 * 3 * 256) return;
  int pj = tid & 15, pi = (tid >> 4) & 15;
  int c = (tid >> 8) % 3;
  int bp = tid / 768;
  int b = bp >> 6;
  const float* pp = par + bp * 8;
  float ta = pp[0], tb = pp[1], tc = pp[2], td = pp[3], tx = pp[4], ty = pp[5];
  float bj = (2.f * pj + 1.f) / 16.f - 1.f;
  float bi = (2.f * pi + 1.f) / 16.f - 1.f;
  float gx = ta * bj + tb * bi + tx;
  float gy = tc * bj + td * bi + ty;
  float xs = ((gx + 1.f) * 128.f - 1.f) * 0.5f;
  float ys = ((gy + 1.f) * 128.f - 1.f) * 0.5f;
  float x0f = floorf(xs), y0f = floorf(ys);
  float wx = xs - x0f, wy = ys - y0f;
  int x0 = (int)x0f, y0 = (int)y0f, x1 = x0 + 1, y1 = y0 + 1;
  const float* img = x + ((size_t)b * 3 + c) * 16384;
  auto g = [&](int yi, int xi) -> float {
    bool v = (xi >= 0) && (xi < 128) && (yi >= 0) && (yi < 128);
    int yc = yi < 0 ? 0 : (yi > 127 ? 127 : yi);
    int xc = xi < 0 ? 0 : (xi > 127 ? 127 : xi);
    float val = img[yc * 128 + xc];
    return v ? val : 0.f;
  };
  float v00 = g(y0, x0), v01 = g(y0, x1), v10 = g(y1, x0), v11 = g(y1, x1);
  out[tid] = v00 * (1.f - wx) * (1.f - wy) + v01 * wx * (1.f - wy) +
             v10 * (1.f - wx) * wy + v11 * wx * wy;
}

extern "C" void kernel_launch(void* const* d_in, const int* in_sizes, int n_in,
                              void* d_out, int out_size, void* d_ws, size_t ws_size,
                              hipStream_t stream) {
  const float* x        = (const float*)d_in[0];
  const float* conv1_w  = (const float*)d_in[1];
  const float* conv1_b  = (const float*)d_in[2];
  const float* a1_in_w  = (const float*)d_in[3];
  const float* a1_in_b  = (const float*)d_in[4];
  const float* a1_qkv_w = (const float*)d_in[5];
  const float* a1_qkv_b = (const float*)d_in[6];
  const float* a1_out_w = (const float*)d_in[7];
  const float* a1_out_b = (const float*)d_in[8];
  const float* a1_proj_w = (const float*)d_in[9];
  const float* a1_proj_b = (const float*)d_in[10];
  const float* conv2_w  = (const float*)d_in[11];
  const float* conv2_b  = (const float*)d_in[12];
  const float* a2_in_w  = (const float*)d_in[13];
  const float* a2_in_b  = (const float*)d_in[14];
  const float* a2_qkv_w = (const float*)d_in[15];
  const float* a2_qkv_b = (const float*)d_in[16];
  const float* a2_out_w = (const float*)d_in[17];
  const float* a2_out_b = (const float*)d_in[18];
  const float* a2_proj_w = (const float*)d_in[19];
  const float* a2_proj_b = (const float*)d_in[20];
  const float* fc1_w    = (const float*)d_in[21];
  const float* fc1_b    = (const float*)d_in[22];
  const float* fc2_w    = (const float*)d_in[23];
  const float* fc2_b    = (const float*)d_in[24];
  float* out = (float*)d_out;

  char* ws = (char*)d_ws;
  float* f1  = (float*)(ws + 0);
  float* y1  = f1;
  float* f2  = (float*)(ws + 134217728);
  float* y2  = f2;
  float* f3  = (float*)(ws + 0);
  float* h1  = (float*)(ws + 67108864);
  float* t   = (float*)(ws + 167772160);
  float* qkv = (float*)(ws + 174063616);
  float* p   = (float*)(ws + 192937984);
  float* o   = (float*)(ws + 195035136);
  float* ao  = (float*)(ws + 201326592);
  float* tp  = (float*)(ws + 207618048);
  float* par = (float*)(ws + 207650816);

  const float scale = 0.07216878364870323f; // 1/sqrt(192)

  conv3x3_relu_c3<<<dim3(64, 64, 32), 256, 0, stream>>>(x, conv1_w, conv1_b, f1);
  gemm_nt<0><<<dim3(12, 32), 256, 0, stream>>>(f1, a1_in_w, a1_in_b, t, 2048, 768, 16384);
  gemm_nt<0><<<dim3(36, 32), 256, 0, stream>>>(t, a1_qkv_w, a1_qkv_b, qkv, 2048, 2304, 768);
  attn_scores<<<dim3(64, 4, 32), 64, 0, stream>>>(qkv, p, scale);
  attn_o<<<6144, 256, 0, stream>>>(p, qkv, o);
  gemm_nt<0><<<dim3(12, 32), 256, 0, stream>>>(o, a1_out_w, a1_out_b, ao, 2048, 768, 768);
  gemm_nt<0><<<dim3(256, 32), 256, 0, stream>>>(ao, a1_proj_w, a1_proj_b, y1, 2048, 16384, 768);
  maxpool2k<<<32768, 256, 0, stream>>>(y1, f2);
  conv3x3_relu_c64_fast<<<dim3(16, 32), 256, 0, stream>>>(f2, conv2_w, conv2_b, f3);
  gemm_nt<0><<<dim3(12, 32), 256, 0, stream>>>(f3, a2_in_w, a2_in_b, t, 2048, 768, 4096);
  gemm_nt<0><<<dim3(36, 32), 256, 0, stream>>>(t, a2_qkv_w, a2_qkv_b, qkv, 2048, 2304, 768);
  attn_scores<<<dim3(64, 4, 32), 64, 0, stream>>>(qkv, p, scale);
  attn_o<<<6144, 256, 0, stream>>>(p, qkv, o);
  gemm_nt<0><<<dim3(12, 32), 256, 0, stream>>>(o, a2_out_w, a2_out_b, ao, 2048, 768, 768);
  gemm_nt<0><<<dim3(64, 32), 256, 0, stream>>>(ao, a2_proj_w, a2_proj_b, y2, 2048, 4096, 768);
  gemm_nt<1><<<dim3(32, 32), 256, 0, stream>>>(y2, fc1_w, fc1_b, h1, 2048, 2048, 4096);
  gemm_small_n<<<32, 256, 0, stream>>>(h1, fc2_w, fc2_b, tp, 2048, 4, 2048);
  params_k<<<32, 64, 0, stream>>>(tp, par, out + 1572864);
  sample_k<<<6144, 256, 0, stream>>>(x, par, out);
}

// Round 3
// 1388.004 us; speedup vs baseline: 3.5877x; 2.7553x over previous
//
#include <hip/hip_runtime.h>
#include <hip/hip_bf16.h>
#include <math.h>

// Shapes (fixed): B=32, C=3, H=128, W=128, HID=64, NP=64, P=16, E=768, NH=4, dh=192
// Output = concat(patches (32*64*3*16*16), translate (32*64*2)), fp32.

#define PI_F 3.14159265358979323846f

typedef float f32x4 __attribute__((ext_vector_type(4)));
typedef short short8 __attribute__((ext_vector_type(8)));
typedef __hip_bfloat16 bf16;

__device__ __forceinline__ void async16(const void* g, void* l) {
  __builtin_amdgcn_global_load_lds(
      (const __attribute__((address_space(1))) void*)g,
      (__attribute__((address_space(3))) void*)l, 16, 0, 0);
}

// ---------------- bf16 MFMA NT GEMM: C[M,N] = A[M,K] * Bw[N,K]^T ----------------
// 128x128 tile, BK=32, 256 threads (4 waves, 2x2 of 64x64), m97-style staging.
// MODE 0: partial fp32 to Cout + z*M*N (no bias); MODE 1: fp32 + bias; MODE 2: bf16 + bias.
template <int MODE>
__global__ __launch_bounds__(256) void gemm_bf16(
    const unsigned short* __restrict__ A, const unsigned short* __restrict__ Bw,
    const float* __restrict__ bias, void* __restrict__ Cout,
    int M, int N, int K, int kchunk) {
  __shared__ unsigned short As[128 * 32];
  __shared__ unsigned short Bs[128 * 32];
  const int tid = threadIdx.x;
  const int bm = blockIdx.y << 7, bn = blockIdx.x << 7;
  const int k0 = blockIdx.z * kchunk;
  const int wave = tid >> 6;
  const int lane = tid & 63;
  const int wm = (wave & 1) << 6, wn = (wave >> 1) << 6;
  // staging map: thread tid -> LDS bytes tid*16 (row=tid>>2 of 32-elem rows, col=(tid&3)*8)
  const int r0 = tid >> 2;
  const int c0 = (tid & 3) << 3;
  const unsigned short* Ag0 = A + (size_t)(bm + r0) * K + k0 + c0;
  const unsigned short* Ag1 = Ag0 + (size_t)64 * K;
  const unsigned short* Bg0 = Bw + (size_t)(bn + r0) * K + k0 + c0;
  const unsigned short* Bg1 = Bg0 + (size_t)64 * K;
  unsigned short* Al = As + wave * 512;   // wave-uniform LDS base (lane*16B implicit)
  unsigned short* Bl = Bs + wave * 512;
  f32x4 acc[4][4] = {};
  const int fr = lane & 15;               // row within 16-tile for A/B frags
  const int fk = (lane >> 4) << 3;        // k offset (0,8,16,24)
  for (int kt = 0; kt < kchunk; kt += 32) {
    async16(Ag0 + kt, Al);
    async16(Ag1 + kt, Al + 2048);
    async16(Bg0 + kt, Bl);
    async16(Bg1 + kt, Bl + 2048);
    __syncthreads();
    short8 af[4], bf[4];
    #pragma unroll
    for (int i = 0; i < 4; ++i)
      af[i] = *(const short8*)(As + ((wm + i * 16 + fr) << 5) + fk);
    #pragma unroll
    for (int i = 0; i < 4; ++i)
      bf[i] = *(const short8*)(Bs + ((wn + i * 16 + fr) << 5) + fk);
    #pragma unroll
    for (int mi = 0; mi < 4; ++mi)
      #pragma unroll
      for (int ni = 0; ni < 4; ++ni)
        acc[mi][ni] = __builtin_amdgcn_mfma_f32_16x16x32_bf16(af[mi], bf[ni], acc[mi][ni], 0, 0, 0);
    __syncthreads();
  }
  const int cr = (lane >> 4) << 2;   // C row base within 16-tile
  const int cc = lane & 15;          // C col within 16-tile
  if (MODE == 0) {
    float* C = (float*)Cout + (size_t)blockIdx.z * M * N;
    #pragma unroll
    for (int mi = 0; mi < 4; ++mi)
      #pragma unroll
      for (int ni = 0; ni < 4; ++ni) {
        int col = bn + wn + ni * 16 + cc;
        #pragma unroll
        for (int r = 0; r < 4; ++r)
          C[(size_t)(bm + wm + mi * 16 + cr + r) * N + col] = acc[mi][ni][r];
      }
  } else {
    #pragma unroll
    for (int ni = 0; ni < 4; ++ni) {
      int col = bn + wn + ni * 16 + cc;
      float bv = bias[col];
      #pragma unroll
      for (int mi = 0; mi < 4; ++mi)
        #pragma unroll
        for (int r = 0; r < 4; ++r) {
          size_t idx = (size_t)(bm + wm + mi * 16 + cr + r) * N + col;
          float v = acc[mi][ni][r] + bv;
          if (MODE == 1) ((float*)Cout)[idx] = v;
          else ((bf16*)Cout)[idx] = __float2bfloat16(v);
        }
    }
  }
}

// ---------------- split-K reduce: out_bf16 = act(sum_z part[z] + bias) ----------------
__global__ __launch_bounds__(256) void reduce_bias_k(
    const float* __restrict__ part, const float* __restrict__ bias,
    bf16* __restrict__ out, int MN, int N, int S, int relu) {
  int i = blockIdx.x * 256 + threadIdx.x;
  if (i >= MN) return;
  float s = 0.f;
  for (int z = 0; z < S; ++z) s += part[(size_t)z * MN + i];
  s += bias[i % N];
  if (relu) s = fmaxf(s, 0.f);
  out[i] = __float2bfloat16(s);
}

// ---------------- fp32 -> bf16 weight conversion ----------------
__global__ __launch_bounds__(256) void cvt_bf16_k(
    const float* __restrict__ src, bf16* __restrict__ dst, int n4) {
  int i = blockIdx.x * 256 + threadIdx.x;
  if (i >= n4) return;
  float4 v = ((const float4*)src)[i];
  bf16* d = dst + (size_t)i * 4;
  d[0] = __float2bfloat16(v.x); d[1] = __float2bfloat16(v.y);
  d[2] = __float2bfloat16(v.z); d[3] = __float2bfloat16(v.w);
}

// ---------------- conv1: (32,3,128,128) -> bf16 (32,64,128,128), 3x3 SAME, ReLU ----------
__global__ __launch_bounds__(256) void conv3x3_relu_c3(
    const float* __restrict__ x, const float* __restrict__ w,
    const float* __restrict__ bias, bf16* __restrict__ out) {
  int tid = threadIdx.x;
  int pix = blockIdx.x * 256 + tid;
  int oc = blockIdx.y, b = blockIdx.z;
  int y = pix >> 7, xx = pix & 127;
  const float* wp = w + oc * 27;
  const float* xb = x + (size_t)b * 3 * 16384;
  float acc = bias[oc];
  #pragma unroll
  for (int ic = 0; ic < 3; ++ic) {
    #pragma unroll
    for (int ky = 0; ky < 3; ++ky) {
      int yy = y + ky - 1;
      if ((unsigned)yy < 128u) {
        const float* xr = xb + ic * 16384 + yy * 128;
        #pragma unroll
        for (int kx = 0; kx < 3; ++kx) {
          int xc = xx + kx - 1;
          if ((unsigned)xc < 128u) acc += wp[ic * 9 + ky * 3 + kx] * xr[xc];
        }
      }
    }
  }
  out[((size_t)(b * 64 + oc)) * 16384 + pix] = __float2bfloat16(fmaxf(acc, 0.f));
}

// ---------------- conv2 (fast): bf16 in (32,64,64,64) -> bf16 out, 3x3 SAME, ReLU --------
#define ICB 8
__global__ __launch_bounds__(256) void conv3x3_relu_c64_fast(
    const bf16* __restrict__ x, const float* __restrict__ w,
    const float* __restrict__ bias, bf16* __restrict__ out) {
  __shared__ float xs[ICB][6][68];
  __shared__ float wsm[ICB][9][64];
  const int tid = threadIdx.x;
  const int b = blockIdx.y;
  const int y0 = blockIdx.x * 4;
  const int xg = (tid & 7) * 8;
  const int row = (tid >> 3) & 3;
  const int oc0 = (tid >> 5) * 8;
  const bf16* xb = x + (size_t)b * 64 * 4096;
  float acc[8][8] = {};
  for (int ic0 = 0; ic0 < 64; ic0 += ICB) {
    for (int i = tid; i < ICB * 6 * 68; i += 256) {
      int c = i % 68;
      int r = (i / 68) % 6;
      int ic = i / (68 * 6);
      int gy = y0 + r - 1;
      int gx = c - 1;
      float v = 0.f;
      if ((unsigned)gy < 64u && (unsigned)gx < 64u)
        v = __bfloat162float(xb[(size_t)(ic0 + ic) * 4096 + gy * 64 + gx]);
      xs[ic][r][c] = v;
    }
    for (int i = tid; i < ICB * 9 * 64; i += 256) {
      int oc = i & 63;
      int k = (i >> 6) % 9;
      int ic = i / (64 * 9);
      wsm[ic][k][oc] = w[(size_t)oc * 576 + (ic0 + ic) * 9 + k];
    }
    __syncthreads();
    #pragma unroll
    for (int ic = 0; ic < ICB; ++ic) {
      #pragma unroll
      for (int ky = 0; ky < 3; ++ky) {
        const float* rp = &xs[ic][row + ky][xg];
        float4 r0 = *(const float4*)(rp);
        float4 r1 = *(const float4*)(rp + 4);
        float4 r2 = *(const float4*)(rp + 8);
        float v[10] = {r0.x, r0.y, r0.z, r0.w, r1.x, r1.y, r1.z, r1.w, r2.x, r2.y};
        #pragma unroll
        for (int kx = 0; kx < 3; ++kx) {
          const float* wr = &wsm[ic][ky * 3 + kx][oc0];
          float4 w0 = *(const float4*)(wr);
          float4 w1 = *(const float4*)(wr + 4);
          float wv[8] = {w0.x, w0.y, w0.z, w0.w, w1.x, w1.y, w1.z, w1.w};
          #pragma unroll
          for (int o = 0; o < 8; ++o)
            #pragma unroll
            for (int p = 0; p < 8; ++p)
              acc[o][p] += wv[o] * v[p + kx];
        }
      }
    }
    __syncthreads();
  }
  #pragma unroll
  for (int o = 0; o < 8; ++o) {
    float bo = bias[oc0 + o];
    bf16* op = out + ((size_t)(b * 64 + oc0 + o)) * 4096 + (y0 + row) * 64 + xg;
    #pragma unroll
    for (int p = 0; p < 8; ++p) op[p] = __float2bfloat16(fmaxf(acc[o][p] + bo, 0.f));
  }
}

// ---------------- attention: scores + softmax (fp32 qkv) ----------------
__global__ __launch_bounds__(64) void attn_scores(
    const float* __restrict__ qkv, float* __restrict__ p, float scale) {
  int tq = blockIdx.x, h = blockIdx.y, b = blockIdx.z;
  int lane = threadIdx.x;
  __shared__ float qrow[192];
  const float* qp = qkv + ((size_t)(b * 64 + tq)) * 2304 + h * 192;
  for (int d = lane; d < 192; d += 64) qrow[d] = qp[d];
  __syncthreads();
  const float* kp = qkv + ((size_t)(b * 64 + lane)) * 2304 + 768 + h * 192;
  float s = 0.f;
  for (int d = 0; d < 192; ++d) s += qrow[d] * kp[d];
  s *= scale;
  float m = s;
  for (int off = 32; off; off >>= 1) m = fmaxf(m, __shfl_xor(m, off));
  float e = expf(s - m);
  float sum = e;
  for (int off = 32; off; off >>= 1) sum += __shfl_xor(sum, off);
  p[(((size_t)b * 4 + h) * 64 + tq) * 64 + lane] = e / sum;
}

// ---------------- attention: o = p @ v, bf16 out ----------------
__global__ __launch_bounds__(256) void attn_o(
    const float* __restrict__ p, const float* __restrict__ qkv, bf16* __restrict__ o) {
  size_t tid = (size_t)blockIdx.x * 256 + threadIdx.x;
  if (tid >= (size_t)32 * 64 * 768) return;
  int e = (int)(tid % 768);
  int tq = (int)((tid / 768) % 64);
  int b = (int)(tid / (768 * 64));
  int h = e / 192;
  const float* pp = p + (((size_t)b * 4 + h) * 64 + tq) * 64;
  const float* vp = qkv + (size_t)b * 64 * 2304 + 1536 + e;
  float acc = 0.f;
  for (int tk = 0; tk < 64; ++tk) acc += pp[tk] * vp[(size_t)tk * 2304];
  o[tid] = __float2bfloat16(acc);
}

// ---------------- maxpool 2x2 stride 2, bf16 ----------------
__global__ __launch_bounds__(256) void maxpool2k(
    const bf16* __restrict__ x, bf16* __restrict__ out) {
  size_t tid = (size_t)blockIdx.x * 256 + threadIdx.x;
  if (tid >= (size_t)32 * 64 * 64 * 64) return;
  int xx = (int)(tid & 63);
  int y = (int)((tid >> 6) & 63);
  size_t plane = tid >> 12;
  const bf16* xp = x + plane * 16384 + (size_t)y * 2 * 128 + xx * 2;
  float a = __bfloat162float(xp[0]), bq = __bfloat162float(xp[1]);
  float c = __bfloat162float(xp[128]), d = __bfloat162float(xp[129]);
  out[tid] = __float2bfloat16(fmaxf(fmaxf(a, bq), fmaxf(c, d)));
}

// ---------------- fc2: tiny-N GEMM (N=4), bf16 A ----------------
__global__ __launch_bounds__(256) void gemm_small_n(
    const bf16* __restrict__ A, const float* __restrict__ Bw,
    const float* __restrict__ bias, float* __restrict__ C,
    int M, int N, int K) {
  int tid = blockIdx.x * 256 + threadIdx.x;
  if (tid >= M * N) return;
  int n = tid % N, m = tid / N;
  const bf16* a = A + (size_t)m * K;
  const float* bb = Bw + (size_t)n * K;
  float acc = bias[n];
  for (int k = 0; k < K; ++k) acc += __bfloat162float(a[k]) * bb[k];
  C[tid] = acc;
}

// ---------------- transform params + translate output ----------------
__global__ __launch_bounds__(64) void params_k(
    const float* __restrict__ tp, float* __restrict__ par, float* __restrict__ trans_out) {
  int m = blockIdx.x * 64 + threadIdx.x;
  if (m >= 2048) return;
  float t0 = tp[m * 4 + 0], t1 = tp[m * 4 + 1], t2 = tp[m * 4 + 2], t3 = tp[m * 4 + 3];
  float trx = tanhf(t0), tryy = tanhf(t1);
  float s = (1.f / (1.f + expf(-t2))) * 0.3f;
  float rot = tanhf(t3) * PI_F;
  float c = cosf(rot), sn = sinf(rot);
  float x_ext = fminf(s * fabsf(c) + s * fabsf(sn), 1.f);
  float y_ext = fminf(s * fabsf(sn) + s * fabsf(c), 1.f);
  float tx = trx * (1.f - x_ext);
  float ty = tryy * (1.f - y_ext);
  par[m * 8 + 0] = s * c;
  par[m * 8 + 1] = -s * sn;
  par[m * 8 + 2] = s * sn;
  par[m * 8 + 3] = s * c;
  par[m * 8 + 4] = tx;
  par[m * 8 + 5] = ty;
  trans_out[m * 2 + 0] = tx;
  trans_out[m * 2 + 1] = ty;
}

// ---------------- bilinear grid sample (fp32 x) ----------------
__global__ __launch_bounds__(256) void sample_k(
    const float* __restrict__ x, const float* __restrict__ par, float* __restrict__ out) {
  int tid = blockIdx.x * 256 + threadIdx.x;
  if (tid >= 32 * 64 * 3 * 256) return;
  int pj = tid & 15, pi = (tid >> 4) & 15;
  int c = (tid >> 8) % 3;
  int bp = tid / 768;
  int b = bp >> 6;
  const float* pp = par + bp * 8;
  float ta = pp[0], tb = pp[1], tc = pp[2], td = pp[3], tx = pp[4], ty = pp[5];
  float bj = (2.f * pj + 1.f) / 16.f - 1.f;
  float bi = (2.f * pi + 1.f) / 16.f - 1.f;
  float gx = ta * bj + tb * bi + tx;
  float gy = tc * bj + td * bi + ty;
  float xs = ((gx + 1.f) * 128.f - 1.f) * 0.5f;
  float ys = ((gy + 1.f) * 128.f - 1.f) * 0.5f;
  float x0f = floorf(xs), y0f = floorf(ys);
  float wx = xs - x0f, wy = ys - y0f;
  int x0 = (int)x0f, y0 = (int)y0f, x1 = x0 + 1, y1 = y0 + 1;
  const float* img = x + ((size_t)b * 3 + c) * 16384;
  auto g = [&](int yi, int xi) -> float {
    bool v = (xi >= 0) && (xi < 128) && (yi >= 0) && (yi < 128);
    int yc = yi < 0 ? 0 : (yi > 127 ? 127 : yi);
    int xc = xi < 0 ? 0 : (xi > 127 ? 127 : xi);
    float val = img[yc * 128 + xc];
    return v ? val : 0.f;
  };
  float v00 = g(y0, x0), v01 = g(y0, x1), v10 = g(y1, x0), v11 = g(y1, x1);
  out[tid] = v00 * (1.f - wx) * (1.f - wy) + v01 * wx * (1.f - wy) +
             v10 * (1.f - wx) * wy + v11 * wx * wy;
}

static inline void cvt(const float* src, bf16* dst, int n, hipStream_t s) {
  int n4 = n / 4;
  cvt_bf16_k<<<(n4 + 255) / 256, 256, 0, s>>>(src, dst, n4);
}

extern "C" void kernel_launch(void* const* d_in, const int* in_sizes, int n_in,
                              void* d_out, int out_size, void* d_ws, size_t ws_size,
                              hipStream_t stream) {
  const float* x        = (const float*)d_in[0];
  const float* conv1_w  = (const float*)d_in[1];
  const float* conv1_b  = (const float*)d_in[2];
  const float* a1_in_w  = (const float*)d_in[3];
  const float* a1_in_b  = (const float*)d_in[4];
  const float* a1_qkv_w = (const float*)d_in[5];
  const float* a1_qkv_b = (const float*)d_in[6];
  const float* a1_out_w = (const float*)d_in[7];
  const float* a1_out_b = (const float*)d_in[8];
  const float* a1_proj_w = (const float*)d_in[9];
  const float* a1_proj_b = (const float*)d_in[10];
  const float* conv2_w  = (const float*)d_in[11];
  const float* conv2_b  = (const float*)d_in[12];
  const float* a2_in_w  = (const float*)d_in[13];
  const float* a2_in_b  = (const float*)d_in[14];
  const float* a2_qkv_w = (const float*)d_in[15];
  const float* a2_qkv_b = (const float*)d_in[16];
  const float* a2_out_w = (const float*)d_in[17];
  const float* a2_out_b = (const float*)d_in[18];
  const float* a2_proj_w = (const float*)d_in[19];
  const float* a2_proj_b = (const float*)d_in[20];
  const float* fc1_w    = (const float*)d_in[21];
  const float* fc1_b    = (const float*)d_in[22];
  const float* fc2_w    = (const float*)d_in[23];
  const float* fc2_b    = (const float*)d_in[24];
  float* out = (float*)d_out;

  // Workspace layout (bytes); peak 206,667,776 <= prior 207.7 MB footprint.
  char* ws = (char*)d_ws;
  bf16*  f1   = (bf16*)(ws + 0);            // 67,108,864 (2048x16384)
  bf16*  y1   = f1;                          // proj1 out, overwrites f1 (dead)
  bf16*  f3   = (bf16*)(ws + 0);            // 16,777,216 conv2 out (y1 dead)
  bf16*  h1   = (bf16*)(ws + 33554432);     // 8,388,608  fc1 out
  bf16*  f2   = (bf16*)(ws + 67108864);     // 16,777,216 pool out
  float* part = (float*)(ws + 83886080);    // 50,331,648 split-K partials
  bf16*  t    = (bf16*)(ws + 134217728);    // 3,145,728
  float* qkv  = (float*)(ws + 137363456);   // 18,874,368
  float* p    = (float*)(ws + 156237824);   // 2,097,152
  bf16*  o    = (bf16*)(ws + 158334976);    // 3,145,728
  bf16*  ao   = (bf16*)(ws + 161480704);    // 3,145,728
  bf16*  y2   = (bf16*)(ws + 164626432);    // 16,777,216
  float* tp   = (float*)(ws + 181403648);   // 32,768
  float* par  = (float*)(ws + 181436416);   // 65,536
  bf16*  W    = (bf16*)(ws + 181501952);    // 25,165,824 weight scratch (reused 9x)

  const unsigned short* Wu = (const unsigned short*)W;
  const float scale = 0.07216878364870323f; // 1/sqrt(192)

  // conv1 -> f1 bf16
  conv3x3_relu_c3<<<dim3(64, 64, 32), 256, 0, stream>>>(x, conv1_w, conv1_b, f1);
  // t1 = f1 @ a1_in_w^T  (split-K 8)
  cvt(a1_in_w, W, 768 * 16384, stream);
  gemm_bf16<0><<<dim3(6, 16, 8), 256, 0, stream>>>((const unsigned short*)f1, Wu, nullptr, part, 2048, 768, 16384, 2048);
  reduce_bias_k<<<6144, 256, 0, stream>>>(part, a1_in_b, t, 2048 * 768, 768, 8, 0);
  // qkv1 (fp32 out for attention)
  cvt(a1_qkv_w, W, 2304 * 768, stream);
  gemm_bf16<1><<<dim3(18, 16, 1), 256, 0, stream>>>((const unsigned short*)t, Wu, a1_qkv_b, qkv, 2048, 2304, 768, 768);
  attn_scores<<<dim3(64, 4, 32), 64, 0, stream>>>(qkv, p, scale);
  attn_o<<<6144, 256, 0, stream>>>(p, qkv, o);
  // out-proj 1 (split-K 3)
  cvt(a1_out_w, W, 768 * 768, stream);
  gemm_bf16<0><<<dim3(6, 16, 3), 256, 0, stream>>>((const unsigned short*)o, Wu, nullptr, part, 2048, 768, 768, 256);
  reduce_bias_k<<<6144, 256, 0, stream>>>(part, a1_out_b, ao, 2048 * 768, 768, 3, 0);
  // proj1 -> y1 bf16
  cvt(a1_proj_w, W, 16384 * 768, stream);
  gemm_bf16<2><<<dim3(128, 16, 1), 256, 0, stream>>>((const unsigned short*)ao, Wu, a1_proj_b, y1, 2048, 16384, 768, 768);
  // pool -> f2
  maxpool2k<<<32768, 256, 0, stream>>>(y1, f2);
  // conv2 -> f3 bf16
  conv3x3_relu_c64_fast<<<dim3(16, 32), 256, 0, stream>>>(f2, conv2_w, conv2_b, f3);
  // t2 (split-K 4)
  cvt(a2_in_w, W, 768 * 4096, stream);
  gemm_bf16<0><<<dim3(6, 16, 4), 256, 0, stream>>>((const unsigned short*)f3, Wu, nullptr, part, 2048, 768, 4096, 1024);
  reduce_bias_k<<<6144, 256, 0, stream>>>(part, a2_in_b, t, 2048 * 768, 768, 4, 0);
  // qkv2
  cvt(a2_qkv_w, W, 2304 * 768, stream);
  gemm_bf16<1><<<dim3(18, 16, 1), 256, 0, stream>>>((const unsigned short*)t, Wu, a2_qkv_b, qkv, 2048, 2304, 768, 768);
  attn_scores<<<dim3(64, 4, 32), 64, 0, stream>>>(qkv, p, scale);
  attn_o<<<6144, 256, 0, stream>>>(p, qkv, o);
  // out-proj 2 (split-K 3)
  cvt(a2_out_w, W, 768 * 768, stream);
  gemm_bf16<0><<<dim3(6, 16, 3), 256, 0, stream>>>((const unsigned short*)o, Wu, nullptr, part, 2048, 768, 768, 256);
  reduce_bias_k<<<6144, 256, 0, stream>>>(part, a2_out_b, ao, 2048 * 768, 768, 3, 0);
  // proj2 -> y2 bf16
  cvt(a2_proj_w, W, 4096 * 768, stream);
  gemm_bf16<2><<<dim3(32, 16, 1), 256, 0, stream>>>((const unsigned short*)ao, Wu, a2_proj_b, y2, 2048, 4096, 768, 768);
  // fc1 (split-K 2) + ReLU -> h1 bf16
  cvt(fc1_w, W, 2048 * 4096, stream);
  gemm_bf16<0><<<dim3(16, 16, 2), 256, 0, stream>>>((const unsigned short*)y2, Wu, nullptr, part, 2048, 2048, 4096, 2048);
  reduce_bias_k<<<16384, 256, 0, stream>>>(part, fc1_b, h1, 2048 * 2048, 2048, 2, 1);
  // fc2
  gemm_small_n<<<32, 256, 0, stream>>>(h1, fc2_w, fc2_b, tp, 2048, 4, 2048);
  params_k<<<32, 64, 0, stream>>>(tp, par, out + 1572864);
  sample_k<<<6144, 256, 0, stream>>>(x, par, out);
}

// Round 4
// 1018.825 us; speedup vs baseline: 4.8878x; 1.3624x over previous
//
#include <hip/hip_runtime.h>
#include <hip/hip_bf16.h>
#include <math.h>

// Shapes (fixed): B=32, C=3, H=128, W=128, HID=64, NP=64, P=16, E=768, NH=4, dh=192
// Output = concat(patches (32*64*3*16*16), translate (32*64*2)), fp32.

#define PI_F 3.14159265358979323846f

typedef float f32x4 __attribute__((ext_vector_type(4)));
typedef short short8 __attribute__((ext_vector_type(8)));
typedef __hip_bfloat16 bf16;

__device__ __forceinline__ void async16(const void* g, void* l) {
  __builtin_amdgcn_global_load_lds(
      (const __attribute__((address_space(1))) void*)g,
      (__attribute__((address_space(3))) void*)l, 16, 0, 0);
}

// ---------------- bf16 MFMA NT GEMM: C[M,N] = A[M,K] * Bw[N,K]^T ----------------
// 128x128 tile, BK=32, 256 threads (4 waves, 2x2 of 64x64), m97-style staging.
// MODE 0: partial fp32 to Cout + z*M*N (no bias); MODE 1: fp32 + bias; MODE 2: bf16 + bias.
template <int MODE>
__global__ __launch_bounds__(256) void gemm_bf16(
    const unsigned short* __restrict__ A, const unsigned short* __restrict__ Bw,
    const float* __restrict__ bias, void* __restrict__ Cout,
    int M, int N, int K, int kchunk) {
  __shared__ unsigned short As[128 * 32];
  __shared__ unsigned short Bs[128 * 32];
  const int tid = threadIdx.x;
  const int bm = blockIdx.y << 7, bn = blockIdx.x << 7;
  const int k0 = blockIdx.z * kchunk;
  const int wave = tid >> 6;
  const int lane = tid & 63;
  const int wm = (wave & 1) << 6, wn = (wave >> 1) << 6;
  const int r0 = tid >> 2;
  const int c0 = (tid & 3) << 3;
  const unsigned short* Ag0 = A + (size_t)(bm + r0) * K + k0 + c0;
  const unsigned short* Ag1 = Ag0 + (size_t)64 * K;
  const unsigned short* Bg0 = Bw + (size_t)(bn + r0) * K + k0 + c0;
  const unsigned short* Bg1 = Bg0 + (size_t)64 * K;
  unsigned short* Al = As + wave * 512;
  unsigned short* Bl = Bs + wave * 512;
  f32x4 acc[4][4] = {};
  const int fr = lane & 15;
  const int fk = (lane >> 4) << 3;
  for (int kt = 0; kt < kchunk; kt += 32) {
    async16(Ag0 + kt, Al);
    async16(Ag1 + kt, Al + 2048);
    async16(Bg0 + kt, Bl);
    async16(Bg1 + kt, Bl + 2048);
    __syncthreads();
    short8 af[4], bf[4];
    #pragma unroll
    for (int i = 0; i < 4; ++i)
      af[i] = *(const short8*)(As + ((wm + i * 16 + fr) << 5) + fk);
    #pragma unroll
    for (int i = 0; i < 4; ++i)
      bf[i] = *(const short8*)(Bs + ((wn + i * 16 + fr) << 5) + fk);
    #pragma unroll
    for (int mi = 0; mi < 4; ++mi)
      #pragma unroll
      for (int ni = 0; ni < 4; ++ni)
        acc[mi][ni] = __builtin_amdgcn_mfma_f32_16x16x32_bf16(af[mi], bf[ni], acc[mi][ni], 0, 0, 0);
    __syncthreads();
  }
  const int cr = (lane >> 4) << 2;
  const int cc = lane & 15;
  if (MODE == 0) {
    float* C = (float*)Cout + (size_t)blockIdx.z * M * N;
    #pragma unroll
    for (int mi = 0; mi < 4; ++mi)
      #pragma unroll
      for (int ni = 0; ni < 4; ++ni) {
        int col = bn + wn + ni * 16 + cc;
        #pragma unroll
        for (int r = 0; r < 4; ++r)
          C[(size_t)(bm + wm + mi * 16 + cr + r) * N + col] = acc[mi][ni][r];
      }
  } else {
    #pragma unroll
    for (int ni = 0; ni < 4; ++ni) {
      int col = bn + wn + ni * 16 + cc;
      float bv = bias[col];
      #pragma unroll
      for (int mi = 0; mi < 4; ++mi)
        #pragma unroll
        for (int r = 0; r < 4; ++r) {
          size_t idx = (size_t)(bm + wm + mi * 16 + cr + r) * N + col;
          float v = acc[mi][ni][r] + bv;
          if (MODE == 1) ((float*)Cout)[idx] = v;
          else ((bf16*)Cout)[idx] = __float2bfloat16(v);
        }
    }
  }
}

// ---------------- split-K reduce: out_bf16 = act(sum_z part[z] + bias) ----------------
__global__ __launch_bounds__(256) void reduce_bias_k(
    const float* __restrict__ part, const float* __restrict__ bias,
    bf16* __restrict__ out, int MN, int N, int S, int relu) {
  int i = blockIdx.x * 256 + threadIdx.x;
  if (i >= MN) return;
  float s = 0.f;
  for (int z = 0; z < S; ++z) s += part[(size_t)z * MN + i];
  s += bias[i % N];
  if (relu) s = fmaxf(s, 0.f);
  out[i] = __float2bfloat16(s);
}

// ---------------- fp32 -> bf16 weight conversion ----------------
__global__ __launch_bounds__(256) void cvt_bf16_k(
    const float* __restrict__ src, bf16* __restrict__ dst, int n4) {
  int i = blockIdx.x * 256 + threadIdx.x;
  if (i >= n4) return;
  float4 v = ((const float4*)src)[i];
  bf16* d = dst + (size_t)i * 4;
  d[0] = __float2bfloat16(v.x); d[1] = __float2bfloat16(v.y);
  d[2] = __float2bfloat16(v.z); d[3] = __float2bfloat16(v.w);
}

// ---------------- conv1 (fast): (32,3,128,128) -> bf16 (32,64,128,128), 3x3 SAME, ReLU ---
// Block: 256 threads -> 2 output rows x 128 cols x all 64 oc, one image.
// Thread: 8 px x 8 oc (64 acc), 1728 FMA. LDS 13.2 KB, single sync.
__global__ __launch_bounds__(256) void conv3x3_relu_c3_fast(
    const float* __restrict__ x, const float* __restrict__ w,
    const float* __restrict__ bias, bf16* __restrict__ out) {
  __shared__ float xs[3][4][132];   // img col c at index c+1
  __shared__ float wsm[3][9][64];   // [ic][k][oc]
  const int tid = threadIdx.x;
  const int b = blockIdx.y;
  const int y0 = blockIdx.x * 2;
  const int xg = (tid & 15) * 8;    // x base 0..120
  const int row = (tid >> 4) & 1;   // 0..1
  const int oc0 = (tid >> 5) * 8;   // 0..56
  for (int i = tid; i < 3 * 4 * 132; i += 256) {
    int c = i % 132;
    int r = (i / 132) % 4;
    int ic = i / (132 * 4);
    int gy = y0 + r - 1;
    int gx = c - 1;
    float v = 0.f;
    if ((unsigned)gy < 128u && (unsigned)gx < 128u)
      v = x[((size_t)(b * 3 + ic) << 14) + gy * 128 + gx];
    xs[ic][r][c] = v;
  }
  for (int i = tid; i < 3 * 9 * 64; i += 256) {
    int oc = i & 63;
    int k = (i >> 6) % 9;
    int ic = i / (64 * 9);
    wsm[ic][k][oc] = w[oc * 27 + ic * 9 + k];
  }
  __syncthreads();
  float acc[8][8] = {};             // [oc][px]
  #pragma unroll
  for (int ic = 0; ic < 3; ++ic) {
    #pragma unroll
    for (int ky = 0; ky < 3; ++ky) {
      const float* rp = &xs[ic][row + ky][xg];
      float4 r0 = *(const float4*)(rp);
      float4 r1 = *(const float4*)(rp + 4);
      float4 r2 = *(const float4*)(rp + 8);
      float v[10] = {r0.x, r0.y, r0.z, r0.w, r1.x, r1.y, r1.z, r1.w, r2.x, r2.y};
      #pragma unroll
      for (int kx = 0; kx < 3; ++kx) {
        const float* wr = &wsm[ic][ky * 3 + kx][oc0];
        float4 w0 = *(const float4*)(wr);
        float4 w1 = *(const float4*)(wr + 4);
        float wv[8] = {w0.x, w0.y, w0.z, w0.w, w1.x, w1.y, w1.z, w1.w};
        #pragma unroll
        for (int o = 0; o < 8; ++o)
          #pragma unroll
          for (int p = 0; p < 8; ++p)
            acc[o][p] += wv[o] * v[p + kx];
      }
    }
  }
  #pragma unroll
  for (int o = 0; o < 8; ++o) {
    float bo = bias[oc0 + o];
    bf16 vals[8];
    #pragma unroll
    for (int p = 0; p < 8; ++p) vals[p] = __float2bfloat16(fmaxf(acc[o][p] + bo, 0.f));
    bf16* op = out + ((size_t)(b * 64 + oc0 + o) << 14) + (y0 + row) * 128 + xg;
    *(uint4*)op = *(const uint4*)vals;
  }
}

// ---------------- conv2 (fast): bf16 in (32,64,64,64) -> bf16 out, 3x3 SAME, ReLU --------
#define ICB 8
__global__ __launch_bounds__(256) void conv3x3_relu_c64_fast(
    const bf16* __restrict__ x, const float* __restrict__ w,
    const float* __restrict__ bias, bf16* __restrict__ out) {
  __shared__ float xs[ICB][6][68];
  __shared__ float wsm[ICB][9][64];
  const int tid = threadIdx.x;
  const int b = blockIdx.y;
  const int y0 = blockIdx.x * 4;
  const int xg = (tid & 7) * 8;
  const int row = (tid >> 3) & 3;
  const int oc0 = (tid >> 5) * 8;
  const bf16* xb = x + (size_t)b * 64 * 4096;
  float acc[8][8] = {};
  for (int ic0 = 0; ic0 < 64; ic0 += ICB) {
    for (int i = tid; i < ICB * 6 * 68; i += 256) {
      int c = i % 68;
      int r = (i / 68) % 6;
      int ic = i / (68 * 6);
      int gy = y0 + r - 1;
      int gx = c - 1;
      float v = 0.f;
      if ((unsigned)gy < 64u && (unsigned)gx < 64u)
        v = __bfloat162float(xb[(size_t)(ic0 + ic) * 4096 + gy * 64 + gx]);
      xs[ic][r][c] = v;
    }
    for (int i = tid; i < ICB * 9 * 64; i += 256) {
      int oc = i & 63;
      int k = (i >> 6) % 9;
      int ic = i / (64 * 9);
      wsm[ic][k][oc] = w[(size_t)oc * 576 + (ic0 + ic) * 9 + k];
    }
    __syncthreads();
    #pragma unroll
    for (int ic = 0; ic < ICB; ++ic) {
      #pragma unroll
      for (int ky = 0; ky < 3; ++ky) {
        const float* rp = &xs[ic][row + ky][xg];
        float4 r0 = *(const float4*)(rp);
        float4 r1 = *(const float4*)(rp + 4);
        float4 r2 = *(const float4*)(rp + 8);
        float v[10] = {r0.x, r0.y, r0.z, r0.w, r1.x, r1.y, r1.z, r1.w, r2.x, r2.y};
        #pragma unroll
        for (int kx = 0; kx < 3; ++kx) {
          const float* wr = &wsm[ic][ky * 3 + kx][oc0];
          float4 w0 = *(const float4*)(wr);
          float4 w1 = *(const float4*)(wr + 4);
          float wv[8] = {w0.x, w0.y, w0.z, w0.w, w1.x, w1.y, w1.z, w1.w};
          #pragma unroll
          for (int o = 0; o < 8; ++o)
            #pragma unroll
            for (int p = 0; p < 8; ++p)
              acc[o][p] += wv[o] * v[p + kx];
        }
      }
    }
    __syncthreads();
  }
  #pragma unroll
  for (int o = 0; o < 8; ++o) {
    float bo = bias[oc0 + o];
    bf16* op = out + ((size_t)(b * 64 + oc0 + o)) * 4096 + (y0 + row) * 64 + xg;
    #pragma unroll
    for (int p = 0; p < 8; ++p) op[p] = __float2bfloat16(fmaxf(acc[o][p] + bo, 0.f));
  }
}

// ---------------- attention: scores + softmax (fp32 qkv) ----------------
__global__ __launch_bounds__(64) void attn_scores(
    const float* __restrict__ qkv, float* __restrict__ p, float scale) {
  int tq = blockIdx.x, h = blockIdx.y, b = blockIdx.z;
  int lane = threadIdx.x;
  __shared__ float qrow[192];
  const float* qp = qkv + ((size_t)(b * 64 + tq)) * 2304 + h * 192;
  for (int d = lane; d < 192; d += 64) qrow[d] = qp[d];
  __syncthreads();
  const float* kp = qkv + ((size_t)(b * 64 + lane)) * 2304 + 768 + h * 192;
  float s = 0.f;
  for (int d = 0; d < 192; ++d) s += qrow[d] * kp[d];
  s *= scale;
  float m = s;
  for (int off = 32; off; off >>= 1) m = fmaxf(m, __shfl_xor(m, off));
  float e = expf(s - m);
  float sum = e;
  for (int off = 32; off; off >>= 1) sum += __shfl_xor(sum, off);
  p[(((size_t)b * 4 + h) * 64 + tq) * 64 + lane] = e / sum;
}

// ---------------- attention: o = p @ v, bf16 out ----------------
__global__ __launch_bounds__(256) void attn_o(
    const float* __restrict__ p, const float* __restrict__ qkv, bf16* __restrict__ o) {
  size_t tid = (size_t)blockIdx.x * 256 + threadIdx.x;
  if (tid >= (size_t)32 * 64 * 768) return;
  int e = (int)(tid % 768);
  int tq = (int)((tid / 768) % 64);
  int b = (int)(tid / (768 * 64));
  int h = e / 192;
  const float* pp = p + (((size_t)b * 4 + h) * 64 + tq) * 64;
  const float* vp = qkv + (size_t)b * 64 * 2304 + 1536 + e;
  float acc = 0.f;
  for (int tk = 0; tk < 64; ++tk) acc += pp[tk] * vp[(size_t)tk * 2304];
  o[tid] = __float2bfloat16(acc);
}

// ---------------- maxpool 2x2 stride 2, bf16 ----------------
__global__ __launch_bounds__(256) void maxpool2k(
    const bf16* __restrict__ x, bf16* __restrict__ out) {
  size_t tid = (size_t)blockIdx.x * 256 + threadIdx.x;
  if (tid >= (size_t)32 * 64 * 64 * 64) return;
  int xx = (int)(tid & 63);
  int y = (int)((tid >> 6) & 63);
  size_t plane = tid >> 12;
  const bf16* xp = x + plane * 16384 + (size_t)y * 2 * 128 + xx * 2;
  float a = __bfloat162float(xp[0]), bq = __bfloat162float(xp[1]);
  float c = __bfloat162float(xp[128]), d = __bfloat162float(xp[129]);
  out[tid] = __float2bfloat16(fmaxf(fmaxf(a, bq), fmaxf(c, d)));
}

// ---------------- fc2: one wave per (m,n), shuffle-reduce dot ----------------
// grid: 2048 blocks (one per m), 256 threads = 4 waves = 4 n values.
__global__ __launch_bounds__(256) void fc2_wave(
    const bf16* __restrict__ A, const float* __restrict__ Bw,
    const float* __restrict__ bias, float* __restrict__ C, int K) {
  int m = blockIdx.x;
  int n = threadIdx.x >> 6;
  int lane = threadIdx.x & 63;
  const bf16* a = A + (size_t)m * K;
  const float* bb = Bw + (size_t)n * K;
  float acc = 0.f;
  for (int k = lane; k < K; k += 64)
    acc += __bfloat162float(a[k]) * bb[k];
  for (int off = 32; off; off >>= 1) acc += __shfl_xor(acc, off);
  if (lane == 0) C[m * 4 + n] = acc + bias[n];
}

// ---------------- transform params + translate output ----------------
__global__ __launch_bounds__(64) void params_k(
    const float* __restrict__ tp, float* __restrict__ par, float* __restrict__ trans_out) {
  int m = blockIdx.x * 64 + threadIdx.x;
  if (m >= 2048) return;
  float t0 = tp[m * 4 + 0], t1 = tp[m * 4 + 1], t2 = tp[m * 4 + 2], t3 = tp[m * 4 + 3];
  float trx = tanhf(t0), tryy = tanhf(t1);
  float s = (1.f / (1.f + expf(-t2))) * 0.3f;
  float rot = tanhf(t3) * PI_F;
  float c = cosf(rot), sn = sinf(rot);
  float x_ext = fminf(s * fabsf(c) + s * fabsf(sn), 1.f);
  float y_ext = fminf(s * fabsf(sn) + s * fabsf(c), 1.f);
  float tx = trx * (1.f - x_ext);
  float ty = tryy * (1.f - y_ext);
  par[m * 8 + 0] = s * c;
  par[m * 8 + 1] = -s * sn;
  par[m * 8 + 2] = s * sn;
  par[m * 8 + 3] = s * c;
  par[m * 8 + 4] = tx;
  par[m * 8 + 5] = ty;
  trans_out[m * 2 + 0] = tx;
  trans_out[m * 2 + 1] = ty;
}

// ---------------- bilinear grid sample (fp32 x) ----------------
__global__ __launch_bounds__(256) void sample_k(
    const float* __restrict__ x, const float* __restrict__ par, float* __restrict__ out) {
  int tid = blockIdx.x * 256 + threadIdx.x;
  if (tid >= 32 * 64 * 3 * 256) return;
  int pj = tid & 15, pi = (tid >> 4) & 15;
  int c = (tid >> 8) % 3;
  int bp = tid / 768;
  int b = bp >> 6;
  const float* pp = par + bp * 8;
  float ta = pp[0], tb = pp[1], tc = pp[2], td = pp[3], tx = pp[4], ty = pp[5];
  float bj = (2.f * pj + 1.f) / 16.f - 1.f;
  float bi = (2.f * pi + 1.f) / 16.f - 1.f;
  float gx = ta * bj + tb * bi + tx;
  float gy = tc * bj + td * bi + ty;
  float xs = ((gx + 1.f) * 128.f - 1.f) * 0.5f;
  float ys = ((gy + 1.f) * 128.f - 1.f) * 0.5f;
  float x0f = floorf(xs), y0f = floorf(ys);
  float wx = xs - x0f, wy = ys - y0f;
  int x0 = (int)x0f, y0 = (int)y0f, x1 = x0 + 1, y1 = y0 + 1;
  const float* img = x + ((size_t)b * 3 + c) * 16384;
  auto g = [&](int yi, int xi) -> float {
    bool v = (xi >= 0) && (xi < 128) && (yi >= 0) && (yi < 128);
    int yc = yi < 0 ? 0 : (yi > 127 ? 127 : yi);
    int xc = xi < 0 ? 0 : (xi > 127 ? 127 : xi);
    float val = img[yc * 128 + xc];
    return v ? val : 0.f;
  };
  float v00 = g(y0, x0), v01 = g(y0, x1), v10 = g(y1, x0), v11 = g(y1, x1);
  out[tid] = v00 * (1.f - wx) * (1.f - wy) + v01 * wx * (1.f - wy) +
             v10 * (1.f - wx) * wy + v11 * wx * wy;
}

static inline void cvt(const float* src, bf16* dst, int n, hipStream_t s) {
  int n4 = n / 4;
  cvt_bf16_k<<<(n4 + 255) / 256, 256, 0, s>>>(src, dst, n4);
}

extern "C" void kernel_launch(void* const* d_in, const int* in_sizes, int n_in,
                              void* d_out, int out_size, void* d_ws, size_t ws_size,
                              hipStream_t stream) {
  const float* x        = (const float*)d_in[0];
  const float* conv1_w  = (const float*)d_in[1];
  const float* conv1_b  = (const float*)d_in[2];
  const float* a1_in_w  = (const float*)d_in[3];
  const float* a1_in_b  = (const float*)d_in[4];
  const float* a1_qkv_w = (const float*)d_in[5];
  const float* a1_qkv_b = (const float*)d_in[6];
  const float* a1_out_w = (const float*)d_in[7];
  const float* a1_out_b = (const float*)d_in[8];
  const float* a1_proj_w = (const float*)d_in[9];
  const float* a1_proj_b = (const float*)d_in[10];
  const float* conv2_w  = (const float*)d_in[11];
  const float* conv2_b  = (const float*)d_in[12];
  const float* a2_in_w  = (const float*)d_in[13];
  const float* a2_in_b  = (const float*)d_in[14];
  const float* a2_qkv_w = (const float*)d_in[15];
  const float* a2_qkv_b = (const float*)d_in[16];
  const float* a2_out_w = (const float*)d_in[17];
  const float* a2_out_b = (const float*)d_in[18];
  const float* a2_proj_w = (const float*)d_in[19];
  const float* a2_proj_b = (const float*)d_in[20];
  const float* fc1_w    = (const float*)d_in[21];
  const float* fc1_b    = (const float*)d_in[22];
  const float* fc2_w    = (const float*)d_in[23];
  const float* fc2_b    = (const float*)d_in[24];
  float* out = (float*)d_out;

  char* ws = (char*)d_ws;
  bf16*  f1   = (bf16*)(ws + 0);
  bf16*  y1   = f1;
  bf16*  f3   = (bf16*)(ws + 0);
  bf16*  h1   = (bf16*)(ws + 33554432);
  bf16*  f2   = (bf16*)(ws + 67108864);
  float* part = (float*)(ws + 83886080);
  bf16*  t    = (bf16*)(ws + 134217728);
  float* qkv  = (float*)(ws + 137363456);
  float* p    = (float*)(ws + 156237824);
  bf16*  o    = (bf16*)(ws + 158334976);
  bf16*  ao   = (bf16*)(ws + 161480704);
  bf16*  y2   = (bf16*)(ws + 164626432);
  float* tp   = (float*)(ws + 181403648);
  float* par  = (float*)(ws + 181436416);
  bf16*  W    = (bf16*)(ws + 181501952);

  const unsigned short* Wu = (const unsigned short*)W;
  const float scale = 0.07216878364870323f; // 1/sqrt(192)

  conv3x3_relu_c3_fast<<<dim3(64, 32), 256, 0, stream>>>(x, conv1_w, conv1_b, f1);
  cvt(a1_in_w, W, 768 * 16384, stream);
  gemm_bf16<0><<<dim3(6, 16, 8), 256, 0, stream>>>((const unsigned short*)f1, Wu, nullptr, part, 2048, 768, 16384, 2048);
  reduce_bias_k<<<6144, 256, 0, stream>>>(part, a1_in_b, t, 2048 * 768, 768, 8, 0);
  cvt(a1_qkv_w, W, 2304 * 768, stream);
  gemm_bf16<1><<<dim3(18, 16, 1), 256, 0, stream>>>((const unsigned short*)t, Wu, a1_qkv_b, qkv, 2048, 2304, 768, 768);
  attn_scores<<<dim3(64, 4, 32), 64, 0, stream>>>(qkv, p, scale);
  attn_o<<<6144, 256, 0, stream>>>(p, qkv, o);
  cvt(a1_out_w, W, 768 * 768, stream);
  gemm_bf16<0><<<dim3(6, 16, 3), 256, 0, stream>>>((const unsigned short*)o, Wu, nullptr, part, 2048, 768, 768, 256);
  reduce_bias_k<<<6144, 256, 0, stream>>>(part, a1_out_b, ao, 2048 * 768, 768, 3, 0);
  cvt(a1_proj_w, W, 16384 * 768, stream);
  gemm_bf16<2><<<dim3(128, 16, 1), 256, 0, stream>>>((const unsigned short*)ao, Wu, a1_proj_b, y1, 2048, 16384, 768, 768);
  maxpool2k<<<32768, 256, 0, stream>>>(y1, f2);
  conv3x3_relu_c64_fast<<<dim3(16, 32), 256, 0, stream>>>(f2, conv2_w, conv2_b, f3);
  cvt(a2_in_w, W, 768 * 4096, stream);
  gemm_bf16<0><<<dim3(6, 16, 4), 256, 0, stream>>>((const unsigned short*)f3, Wu, nullptr, part, 2048, 768, 4096, 1024);
  reduce_bias_k<<<6144, 256, 0, stream>>>(part, a2_in_b, t, 2048 * 768, 768, 4, 0);
  cvt(a2_qkv_w, W, 2304 * 768, stream);
  gemm_bf16<1><<<dim3(18, 16, 1), 256, 0, stream>>>((const unsigned short*)t, Wu, a2_qkv_b, qkv, 2048, 2304, 768, 768);
  attn_scores<<<dim3(64, 4, 32), 64, 0, stream>>>(qkv, p, scale);
  attn_o<<<6144, 256, 0, stream>>>(p, qkv, o);
  cvt(a2_out_w, W, 768 * 768, stream);
  gemm_bf16<0><<<dim3(6, 16, 3), 256, 0, stream>>>((const unsigned short*)o, Wu, nullptr, part, 2048, 768, 768, 256);
  reduce_bias_k<<<6144, 256, 0, stream>>>(part, a2_out_b, ao, 2048 * 768, 768, 3, 0);
  cvt(a2_proj_w, W, 4096 * 768, stream);
  gemm_bf16<2><<<dim3(32, 16, 1), 256, 0, stream>>>((const unsigned short*)ao, Wu, a2_proj_b, y2, 2048, 4096, 768, 768);
  cvt(fc1_w, W, 2048 * 4096, stream);
  gemm_bf16<0><<<dim3(16, 16, 2), 256, 0, stream>>>((const unsigned short*)y2, Wu, nullptr, part, 2048, 2048, 4096, 2048);
  reduce_bias_k<<<16384, 256, 0, stream>>>(part, fc1_b, h1, 2048 * 2048, 2048, 2, 1);
  fc2_wave<<<2048, 256, 0, stream>>>(h1, fc2_w, fc2_b, tp, 2048);
  params_k<<<32, 64, 0, stream>>>(tp, par, out + 1572864);
  sample_k<<<6144, 256, 0, stream>>>(x, par, out);
}

// Round 5
// 940.989 us; speedup vs baseline: 5.2921x; 1.0827x over previous
//
#include <hip/hip_runtime.h>
#include <hip/hip_bf16.h>
#include <math.h>

// Shapes (fixed): B=32, C=3, H=128, W=128, HID=64, NP=64, P=16, E=768, NH=4, dh=192
// Output = concat(patches (32*64*3*16*16), translate (32*64*2)), fp32.

#define PI_F 3.14159265358979323846f

typedef float f32x4 __attribute__((ext_vector_type(4)));
typedef short short8 __attribute__((ext_vector_type(8)));
typedef unsigned short us4 __attribute__((ext_vector_type(4)));
typedef __hip_bfloat16 bf16;

__device__ __forceinline__ void async16(const void* g, void* l) {
  __builtin_amdgcn_global_load_lds(
      (const __attribute__((address_space(1))) void*)g,
      (__attribute__((address_space(3))) void*)l, 16, 0, 0);
}

// ---------------- bf16 MFMA NT GEMM: C[M,N] = A[M,K] * Bw[N,K]^T ----------------
// 128x128 tile, BK=32, 256 threads (4 waves, 2x2 of 64x64), m97-style staging.
// MODE 0: partial fp32 to Cout + z*M*N (no bias); MODE 1: fp32 + bias; MODE 2: bf16 + bias.
template <int MODE>
__global__ __launch_bounds__(256) void gemm_bf16(
    const unsigned short* __restrict__ A, const unsigned short* __restrict__ Bw,
    const float* __restrict__ bias, void* __restrict__ Cout,
    int M, int N, int K, int kchunk) {
  __shared__ unsigned short As[128 * 32];
  __shared__ unsigned short Bs[128 * 32];
  const int tid = threadIdx.x;
  const int bm = blockIdx.y << 7, bn = blockIdx.x << 7;
  const int k0 = blockIdx.z * kchunk;
  const int wave = tid >> 6;
  const int lane = tid & 63;
  const int wm = (wave & 1) << 6, wn = (wave >> 1) << 6;
  const int r0 = tid >> 2;
  const int c0 = (tid & 3) << 3;
  const unsigned short* Ag0 = A + (size_t)(bm + r0) * K + k0 + c0;
  const unsigned short* Ag1 = Ag0 + (size_t)64 * K;
  const unsigned short* Bg0 = Bw + (size_t)(bn + r0) * K + k0 + c0;
  const unsigned short* Bg1 = Bg0 + (size_t)64 * K;
  unsigned short* Al = As + wave * 512;
  unsigned short* Bl = Bs + wave * 512;
  f32x4 acc[4][4] = {};
  const int fr = lane & 15;
  const int fk = (lane >> 4) << 3;
  for (int kt = 0; kt < kchunk; kt += 32) {
    async16(Ag0 + kt, Al);
    async16(Ag1 + kt, Al + 2048);
    async16(Bg0 + kt, Bl);
    async16(Bg1 + kt, Bl + 2048);
    __syncthreads();
    short8 af[4], bf[4];
    #pragma unroll
    for (int i = 0; i < 4; ++i)
      af[i] = *(const short8*)(As + ((wm + i * 16 + fr) << 5) + fk);
    #pragma unroll
    for (int i = 0; i < 4; ++i)
      bf[i] = *(const short8*)(Bs + ((wn + i * 16 + fr) << 5) + fk);
    #pragma unroll
    for (int mi = 0; mi < 4; ++mi)
      #pragma unroll
      for (int ni = 0; ni < 4; ++ni)
        acc[mi][ni] = __builtin_amdgcn_mfma_f32_16x16x32_bf16(af[mi], bf[ni], acc[mi][ni], 0, 0, 0);
    __syncthreads();
  }
  const int cr = (lane >> 4) << 2;
  const int cc = lane & 15;
  if (MODE == 0) {
    float* C = (float*)Cout + (size_t)blockIdx.z * M * N;
    #pragma unroll
    for (int mi = 0; mi < 4; ++mi)
      #pragma unroll
      for (int ni = 0; ni < 4; ++ni) {
        int col = bn + wn + ni * 16 + cc;
        #pragma unroll
        for (int r = 0; r < 4; ++r)
          C[(size_t)(bm + wm + mi * 16 + cr + r) * N + col] = acc[mi][ni][r];
      }
  } else {
    #pragma unroll
    for (int ni = 0; ni < 4; ++ni) {
      int col = bn + wn + ni * 16 + cc;
      float bv = bias[col];
      #pragma unroll
      for (int mi = 0; mi < 4; ++mi)
        #pragma unroll
        for (int r = 0; r < 4; ++r) {
          size_t idx = (size_t)(bm + wm + mi * 16 + cr + r) * N + col;
          float v = acc[mi][ni][r] + bv;
          if (MODE == 1) ((float*)Cout)[idx] = v;
          else ((bf16*)Cout)[idx] = __float2bfloat16(v);
        }
    }
  }
}

// ---------------- split-K reduce: out_bf16 = act(sum_z part[z] + bias) ----------------
__global__ __launch_bounds__(256) void reduce_bias_k(
    const float* __restrict__ part, const float* __restrict__ bias,
    bf16* __restrict__ out, int MN, int N, int S, int relu) {
  int i = blockIdx.x * 256 + threadIdx.x;
  if (i >= MN) return;
  float s = 0.f;
  for (int z = 0; z < S; ++z) s += part[(size_t)z * MN + i];
  s += bias[i % N];
  if (relu) s = fmaxf(s, 0.f);
  out[i] = __float2bfloat16(s);
}

// ---------------- fp32 -> bf16 weight conversion ----------------
__global__ __launch_bounds__(256) void cvt_bf16_k(
    const float* __restrict__ src, bf16* __restrict__ dst, int n4) {
  int i = blockIdx.x * 256 + threadIdx.x;
  if (i >= n4) return;
  float4 v = ((const float4*)src)[i];
  bf16* d = dst + (size_t)i * 4;
  d[0] = __float2bfloat16(v.x); d[1] = __float2bfloat16(v.y);
  d[2] = __float2bfloat16(v.z); d[3] = __float2bfloat16(v.w);
}

// ---------------- conv2 weight transpose: wcl[tap][oc][ic] bf16 ----------------
__global__ __launch_bounds__(256) void cvt_wcl_k(
    const float* __restrict__ w, bf16* __restrict__ wcl) {
  int i = blockIdx.x * 256 + threadIdx.x;   // 9*64*64 = 36864
  if (i >= 36864) return;
  int ic = i & 63, oc = (i >> 6) & 63, s = i >> 12;
  wcl[i] = __float2bfloat16(w[oc * 576 + ic * 9 + s]);
}

// ---------------- conv1 (fast): (32,3,128,128) -> bf16 (32,64,128,128), 3x3 SAME, ReLU ---
__global__ __launch_bounds__(256) void conv3x3_relu_c3_fast(
    const float* __restrict__ x, const float* __restrict__ w,
    const float* __restrict__ bias, bf16* __restrict__ out) {
  __shared__ float xs[3][4][132];   // img col c at index c+1
  __shared__ float wsm[3][9][64];   // [ic][k][oc]
  const int tid = threadIdx.x;
  const int b = blockIdx.y;
  const int y0 = blockIdx.x * 2;
  const int xg = (tid & 15) * 8;
  const int row = (tid >> 4) & 1;
  const int oc0 = (tid >> 5) * 8;
  for (int i = tid; i < 3 * 4 * 132; i += 256) {
    int c = i % 132;
    int r = (i / 132) % 4;
    int ic = i / (132 * 4);
    int gy = y0 + r - 1;
    int gx = c - 1;
    float v = 0.f;
    if ((unsigned)gy < 128u && (unsigned)gx < 128u)
      v = x[((size_t)(b * 3 + ic) << 14) + gy * 128 + gx];
    xs[ic][r][c] = v;
  }
  for (int i = tid; i < 3 * 9 * 64; i += 256) {
    int oc = i & 63;
    int k = (i >> 6) % 9;
    int ic = i / (64 * 9);
    wsm[ic][k][oc] = w[oc * 27 + ic * 9 + k];
  }
  __syncthreads();
  float acc[8][8] = {};
  #pragma unroll
  for (int ic = 0; ic < 3; ++ic) {
    #pragma unroll
    for (int ky = 0; ky < 3; ++ky) {
      const float* rp = &xs[ic][row + ky][xg];
      float4 r0 = *(const float4*)(rp);
      float4 r1 = *(const float4*)(rp + 4);
      float4 r2 = *(const float4*)(rp + 8);
      float v[10] = {r0.x, r0.y, r0.z, r0.w, r1.x, r1.y, r1.z, r1.w, r2.x, r2.y};
      #pragma unroll
      for (int kx = 0; kx < 3; ++kx) {
        const float* wr = &wsm[ic][ky * 3 + kx][oc0];
        float4 w0 = *(const float4*)(wr);
        float4 w1 = *(const float4*)(wr + 4);
        float wv[8] = {w0.x, w0.y, w0.z, w0.w, w1.x, w1.y, w1.z, w1.w};
        #pragma unroll
        for (int o = 0; o < 8; ++o)
          #pragma unroll
          for (int p = 0; p < 8; ++p)
            acc[o][p] += wv[o] * v[p + kx];
      }
    }
  }
  #pragma unroll
  for (int o = 0; o < 8; ++o) {
    float bo = bias[oc0 + o];
    bf16 vals[8];
    #pragma unroll
    for (int p = 0; p < 8; ++p) vals[p] = __float2bfloat16(fmaxf(acc[o][p] + bo, 0.f));
    bf16* op = out + ((size_t)(b * 64 + oc0 + o) << 14) + (y0 + row) * 128 + xg;
    *(uint4*)op = *(const uint4*)vals;
  }
}

// ---------------- maxpool 2x2 -> channels-last padded xp[b][66][66][64] bf16 -------------
// One wave per padded cell; lane = channel. Borders write zero.
__global__ __launch_bounds__(256) void maxpool_cl(
    const bf16* __restrict__ y1, bf16* __restrict__ xp) {
  int wave = threadIdx.x >> 6;
  int lane = threadIdx.x & 63;          // channel
  int cell = blockIdx.x * 4 + wave;     // 0..4355
  int b = blockIdx.y;
  int yp = cell / 66, xq = cell % 66;
  bf16* dst = xp + (((size_t)b * 66 + yp) * 66 + xq) * 64 + lane;
  if (yp == 0 || yp == 65 || xq == 0 || xq == 65) {
    *dst = __float2bfloat16(0.f);
    return;
  }
  int py = yp - 1, px = xq - 1;
  const bf16* sp = y1 + ((size_t)(b * 64 + lane) << 14) + (py * 2) * 128 + px * 2;
  float a = __bfloat162float(sp[0]), bq = __bfloat162float(sp[1]);
  float c = __bfloat162float(sp[128]), d = __bfloat162float(sp[129]);
  *dst = __float2bfloat16(fmaxf(fmaxf(a, bq), fmaxf(c, d)));
}

// ---------------- conv2 MFMA: xp (padded CL) -> f3[b][oc][4096] bf16, bias+ReLU ----------
// Block: 2 output rows x 64 oc (M=128, N=64), 4 waves as 2x2 (64px x 32oc each).
// K = 9 taps x 64 ic, chunks of 32. A-tile per (tap,chunk) is contiguous per px row.
__global__ __launch_bounds__(256) void conv2_mfma(
    const bf16* __restrict__ xp, const bf16* __restrict__ wcl,
    const float* __restrict__ bias, bf16* __restrict__ f3) {
  __shared__ unsigned short As[128 * 32];   // [px][ic_chunk]
  __shared__ unsigned short Bs[64 * 32];    // [oc][ic_chunk]
  const int tid = threadIdx.x;
  const int b = blockIdx.y;
  const int y0 = blockIdx.x * 2;
  const int wave = tid >> 6;
  const int lane = tid & 63;
  const int wm = (wave & 1) << 6;       // 0 or 64 (px)
  const int wn = (wave >> 1) << 5;      // 0 or 32 (oc)
  const char* xpB = (const char*)(xp + (size_t)b * 66 * 66 * 64);
  const char* wclB = (const char*)wcl;
  // staging: thread covers A slots tid (px=tid>>2, row y0) and tid+256 (px-64=tid>>2, row y0+1)
  const int sr = tid >> 2;               // 0..63
  const int soff = (tid & 3) << 4;       // byte offset within 64B chunk
  unsigned short* Al = As + wave * 512;  // wave-uniform bases (lane*16B implicit)
  unsigned short* Bl = Bs + wave * 512;
  f32x4 acc[4][2] = {};
  const int fr = lane & 15;
  const int fk = (lane >> 4) << 3;
  for (int tap = 0; tap < 9; ++tap) {
    int dy = tap / 3, dx = tap % 3;
    const char* arow0 = xpB + (((y0 + dy) * 66 + dx) << 7);   // *128 bytes per padded col
    const char* brow = wclB + (tap << 13);                    // tap*64oc*64ic*2B
    #pragma unroll
    for (int ch = 0; ch < 2; ++ch) {
      int coff = (ch << 6) + soff;   // chunk byte offset within 128B ic-row
      async16(arow0 + sr * 128 + coff, Al);
      async16(arow0 + 66 * 128 + sr * 128 + coff, Al + 2048);
      async16(brow + sr * 128 + coff, Bl);
      __syncthreads();
      short8 af[4], bf[2];
      #pragma unroll
      for (int i = 0; i < 4; ++i)
        af[i] = *(const short8*)(As + ((wm + i * 16 + fr) << 5) + fk);
      #pragma unroll
      for (int i = 0; i < 2; ++i)
        bf[i] = *(const short8*)(Bs + ((wn + i * 16 + fr) << 5) + fk);
      #pragma unroll
      for (int mi = 0; mi < 4; ++mi)
        #pragma unroll
        for (int ni = 0; ni < 2; ++ni)
          acc[mi][ni] = __builtin_amdgcn_mfma_f32_16x16x32_bf16(af[mi], bf[ni], acc[mi][ni], 0, 0, 0);
      __syncthreads();
    }
  }
  const int cr = (lane >> 4) << 2;
  const int cc = lane & 15;
  #pragma unroll
  for (int ni = 0; ni < 2; ++ni) {
    int oc = wn + ni * 16 + cc;
    float bv = bias[oc];
    #pragma unroll
    for (int mi = 0; mi < 4; ++mi) {
      int pxb = wm + mi * 16 + cr;            // 4 consecutive px, same output row
      int y = y0 + (pxb >> 6), xb = pxb & 63;
      bf16 vals[4];
      #pragma unroll
      for (int r = 0; r < 4; ++r)
        vals[r] = __float2bfloat16(fmaxf(acc[mi][ni][r] + bv, 0.f));
      bf16* op = f3 + (((size_t)(b * 64 + oc)) << 12) + y * 64 + xb;
      *(us4*)op = *(const us4*)vals;
    }
  }
}

// ---------------- attention: scores + softmax (fp32 qkv) ----------------
__global__ __launch_bounds__(64) void attn_scores(
    const float* __restrict__ qkv, float* __restrict__ p, float scale) {
  int tq = blockIdx.x, h = blockIdx.y, b = blockIdx.z;
  int lane = threadIdx.x;
  __shared__ float qrow[192];
  const float* qp = qkv + ((size_t)(b * 64 + tq)) * 2304 + h * 192;
  for (int d = lane; d < 192; d += 64) qrow[d] = qp[d];
  __syncthreads();
  const float* kp = qkv + ((size_t)(b * 64 + lane)) * 2304 + 768 + h * 192;
  float s = 0.f;
  for (int d = 0; d < 192; ++d) s += qrow[d] * kp[d];
  s *= scale;
  float m = s;
  for (int off = 32; off; off >>= 1) m = fmaxf(m, __shfl_xor(m, off));
  float e = expf(s - m);
  float sum = e;
  for (int off = 32; off; off >>= 1) sum += __shfl_xor(sum, off);
  p[(((size_t)b * 4 + h) * 64 + tq) * 64 + lane] = e / sum;
}

// ---------------- attention: o = p @ v, bf16 out ----------------
__global__ __launch_bounds__(256) void attn_o(
    const float* __restrict__ p, const float* __restrict__ qkv, bf16* __restrict__ o) {
  size_t tid = (size_t)blockIdx.x * 256 + threadIdx.x;
  if (tid >= (size_t)32 * 64 * 768) return;
  int e = (int)(tid % 768);
  int tq = (int)((tid / 768) % 64);
  int b = (int)(tid / (768 * 64));
  int h = e / 192;
  const float* pp = p + (((size_t)b * 4 + h) * 64 + tq) * 64;
  const float* vp = qkv + (size_t)b * 64 * 2304 + 1536 + e;
  float acc = 0.f;
  for (int tk = 0; tk < 64; ++tk) acc += pp[tk] * vp[(size_t)tk * 2304];
  o[tid] = __float2bfloat16(acc);
}

// ---------------- fc2: one wave per (m,n), shuffle-reduce dot ----------------
__global__ __launch_bounds__(256) void fc2_wave(
    const bf16* __restrict__ A, const float* __restrict__ Bw,
    const float* __restrict__ bias, float* __restrict__ C, int K) {
  int m = blockIdx.x;
  int n = threadIdx.x >> 6;
  int lane = threadIdx.x & 63;
  const bf16* a = A + (size_t)m * K;
  const float* bb = Bw + (size_t)n * K;
  float acc = 0.f;
  for (int k = lane; k < K; k += 64)
    acc += __bfloat162float(a[k]) * bb[k];
  for (int off = 32; off; off >>= 1) acc += __shfl_xor(acc, off);
  if (lane == 0) C[m * 4 + n] = acc + bias[n];
}

// ---------------- transform params + translate output ----------------
__global__ __launch_bounds__(64) void params_k(
    const float* __restrict__ tp, float* __restrict__ par, float* __restrict__ trans_out) {
  int m = blockIdx.x * 64 + threadIdx.x;
  if (m >= 2048) return;
  float t0 = tp[m * 4 + 0], t1 = tp[m * 4 + 1], t2 = tp[m * 4 + 2], t3 = tp[m * 4 + 3];
  float trx = tanhf(t0), tryy = tanhf(t1);
  float s = (1.f / (1.f + expf(-t2))) * 0.3f;
  float rot = tanhf(t3) * PI_F;
  float c = cosf(rot), sn = sinf(rot);
  float x_ext = fminf(s * fabsf(c) + s * fabsf(sn), 1.f);
  float y_ext = fminf(s * fabsf(sn) + s * fabsf(c), 1.f);
  float tx = trx * (1.f - x_ext);
  float ty = tryy * (1.f - y_ext);
  par[m * 8 + 0] = s * c;
  par[m * 8 + 1] = -s * sn;
  par[m * 8 + 2] = s * sn;
  par[m * 8 + 3] = s * c;
  par[m * 8 + 4] = tx;
  par[m * 8 + 5] = ty;
  trans_out[m * 2 + 0] = tx;
  trans_out[m * 2 + 1] = ty;
}

// ---------------- bilinear grid sample (fp32 x) ----------------
__global__ __launch_bounds__(256) void sample_k(
    const float* __restrict__ x, const float* __restrict__ par, float* __restrict__ out) {
  int tid = blockIdx.x * 256 + threadIdx.x;
  if (tid >= 32 * 64 * 3 * 256) return;
  int pj = tid & 15, pi = (tid >> 4) & 15;
  int c = (tid >> 8) % 3;
  int bp = tid / 768;
  int b = bp >> 6;
  const float* pp = par + bp * 8;
  float ta = pp[0], tb = pp[1], tc = pp[2], td = pp[3], tx = pp[4], ty = pp[5];
  float bj = (2.f * pj + 1.f) / 16.f - 1.f;
  float bi = (2.f * pi + 1.f) / 16.f - 1.f;
  float gx = ta * bj + tb * bi + tx;
  float gy = tc * bj + td * bi + ty;
  float xs = ((gx + 1.f) * 128.f - 1.f) * 0.5f;
  float ys = ((gy + 1.f) * 128.f - 1.f) * 0.5f;
  float x0f = floorf(xs), y0f = floorf(ys);
  float wx = xs - x0f, wy = ys - y0f;
  int x0 = (int)x0f, y0 = (int)y0f, x1 = x0 + 1, y1 = y0 + 1;
  const float* img = x + ((size_t)b * 3 + c) * 16384;
  auto g = [&](int yi, int xi) -> float {
    bool v = (xi >= 0) && (xi < 128) && (yi >= 0) && (yi < 128);
    int yc = yi < 0 ? 0 : (yi > 127 ? 127 : yi);
    int xc = xi < 0 ? 0 : (xi > 127 ? 127 : xi);
    float val = img[yc * 128 + xc];
    return v ? val : 0.f;
  };
  float v00 = g(y0, x0), v01 = g(y0, x1), v10 = g(y1, x0), v11 = g(y1, x1);
  out[tid] = v00 * (1.f - wx) * (1.f - wy) + v01 * wx * (1.f - wy) +
             v10 * (1.f - wx) * wy + v11 * wx * wy;
}

static inline void cvt(const float* src, bf16* dst, int n, hipStream_t s) {
  int n4 = n / 4;
  cvt_bf16_k<<<(n4 + 255) / 256, 256, 0, s>>>(src, dst, n4);
}

extern "C" void kernel_launch(void* const* d_in, const int* in_sizes, int n_in,
                              void* d_out, int out_size, void* d_ws, size_t ws_size,
                              hipStream_t stream) {
  const float* x        = (const float*)d_in[0];
  const float* conv1_w  = (const float*)d_in[1];
  const float* conv1_b  = (const float*)d_in[2];
  const float* a1_in_w  = (const float*)d_in[3];
  const float* a1_in_b  = (const float*)d_in[4];
  const float* a1_qkv_w = (const float*)d_in[5];
  const float* a1_qkv_b = (const float*)d_in[6];
  const float* a1_out_w = (const float*)d_in[7];
  const float* a1_out_b = (const float*)d_in[8];
  const float* a1_proj_w = (const float*)d_in[9];
  const float* a1_proj_b = (const float*)d_in[10];
  const float* conv2_w  = (const float*)d_in[11];
  const float* conv2_b  = (const float*)d_in[12];
  const float* a2_in_w  = (const float*)d_in[13];
  const float* a2_in_b  = (const float*)d_in[14];
  const float* a2_qkv_w = (const float*)d_in[15];
  const float* a2_qkv_b = (const float*)d_in[16];
  const float* a2_out_w = (const float*)d_in[17];
  const float* a2_out_b = (const float*)d_in[18];
  const float* a2_proj_w = (const float*)d_in[19];
  const float* a2_proj_b = (const float*)d_in[20];
  const float* fc1_w    = (const float*)d_in[21];
  const float* fc1_b    = (const float*)d_in[22];
  const float* fc2_w    = (const float*)d_in[23];
  const float* fc2_b    = (const float*)d_in[24];
  float* out = (float*)d_out;

  char* ws = (char*)d_ws;
  bf16*  f1   = (bf16*)(ws + 0);            // conv1 out / proj1 out (y1)
  bf16*  y1   = f1;
  bf16*  f3   = (bf16*)(ws + 0);            // conv2 out (y1 dead)
  bf16*  h1   = (bf16*)(ws + 33554432);
  float* part = (float*)(ws + 83886080);    // split-K partials (50 MB)
  bf16*  xp   = (bf16*)(ws + 83886080);     // padded CL pool out (17.8 MB, part dead here)
  bf16*  t    = (bf16*)(ws + 134217728);
  float* qkv  = (float*)(ws + 137363456);
  float* p    = (float*)(ws + 156237824);
  bf16*  o    = (bf16*)(ws + 158334976);
  bf16*  ao   = (bf16*)(ws + 161480704);
  bf16*  y2   = (bf16*)(ws + 164626432);
  float* tp   = (float*)(ws + 181403648);
  float* par  = (float*)(ws + 181436416);
  bf16*  W    = (bf16*)(ws + 181501952);    // weight scratch (reused)
  bf16*  wcl  = W;                          // conv2 weights [tap][oc][ic] (W free here)

  const unsigned short* Wu = (const unsigned short*)W;
  const float scale = 0.07216878364870323f; // 1/sqrt(192)

  conv3x3_relu_c3_fast<<<dim3(64, 32), 256, 0, stream>>>(x, conv1_w, conv1_b, f1);
  cvt(a1_in_w, W, 768 * 16384, stream);
  gemm_bf16<0><<<dim3(6, 16, 8), 256, 0, stream>>>((const unsigned short*)f1, Wu, nullptr, part, 2048, 768, 16384, 2048);
  reduce_bias_k<<<6144, 256, 0, stream>>>(part, a1_in_b, t, 2048 * 768, 768, 8, 0);
  cvt(a1_qkv_w, W, 2304 * 768, stream);
  gemm_bf16<1><<<dim3(18, 16, 1), 256, 0, stream>>>((const unsigned short*)t, Wu, a1_qkv_b, qkv, 2048, 2304, 768, 768);
  attn_scores<<<dim3(64, 4, 32), 64, 0, stream>>>(qkv, p, scale);
  attn_o<<<6144, 256, 0, stream>>>(p, qkv, o);
  cvt(a1_out_w, W, 768 * 768, stream);
  gemm_bf16<0><<<dim3(6, 16, 3), 256, 0, stream>>>((const unsigned short*)o, Wu, nullptr, part, 2048, 768, 768, 256);
  reduce_bias_k<<<6144, 256, 0, stream>>>(part, a1_out_b, ao, 2048 * 768, 768, 3, 0);
  cvt(a1_proj_w, W, 16384 * 768, stream);
  gemm_bf16<2><<<dim3(128, 16, 1), 256, 0, stream>>>((const unsigned short*)ao, Wu, a1_proj_b, y1, 2048, 16384, 768, 768);
  // conv2 prep: weights [tap][oc][ic] + padded channels-last pool output
  cvt_wcl_k<<<144, 256, 0, stream>>>(conv2_w, wcl);
  maxpool_cl<<<dim3(1089, 32), 256, 0, stream>>>(y1, xp);
  conv2_mfma<<<dim3(32, 32), 256, 0, stream>>>(xp, wcl, conv2_b, f3);
  cvt(a2_in_w, W, 768 * 4096, stream);
  gemm_bf16<0><<<dim3(6, 16, 4), 256, 0, stream>>>((const unsigned short*)f3, Wu, nullptr, part, 2048, 768, 4096, 1024);
  reduce_bias_k<<<6144, 256, 0, stream>>>(part, a2_in_b, t, 2048 * 768, 768, 4, 0);
  cvt(a2_qkv_w, W, 2304 * 768, stream);
  gemm_bf16<1><<<dim3(18, 16, 1), 256, 0, stream>>>((const unsigned short*)t, Wu, a2_qkv_b, qkv, 2048, 2304, 768, 768);
  attn_scores<<<dim3(64, 4, 32), 64, 0, stream>>>(qkv, p, scale);
  attn_o<<<6144, 256, 0, stream>>>(p, qkv, o);
  cvt(a2_out_w, W, 768 * 768, stream);
  gemm_bf16<0><<<dim3(6, 16, 3), 256, 0, stream>>>((const unsigned short*)o, Wu, nullptr, part, 2048, 768, 768, 256);
  reduce_bias_k<<<6144, 256, 0, stream>>>(part, a2_out_b, ao, 2048 * 768, 768, 3, 0);
  cvt(a2_proj_w, W, 4096 * 768, stream);
  gemm_bf16<2><<<dim3(32, 16, 1), 256, 0, stream>>>((const unsigned short*)ao, Wu, a2_proj_b, y2, 2048, 4096, 768, 768);
  cvt(fc1_w, W, 2048 * 4096, stream);
  gemm_bf16<0><<<dim3(16, 16, 2), 256, 0, stream>>>((const unsigned short*)y2, Wu, nullptr, part, 2048, 2048, 4096, 2048);
  reduce_bias_k<<<16384, 256, 0, stream>>>(part, fc1_b, h1, 2048 * 2048, 2048, 2, 1);
  fc2_wave<<<2048, 256, 0, stream>>>(h1, fc2_w, fc2_b, tp, 2048);
  params_k<<<32, 64, 0, stream>>>(tp, par, out + 1572864);
  sample_k<<<6144, 256, 0, stream>>>(x, par, out);
}

// Round 6
// 902.346 us; speedup vs baseline: 5.5187x; 1.0428x over previous
//
#include <hip/hip_runtime.h>
#include <hip/hip_bf16.h>
#include <math.h>

// Shapes (fixed): B=32, C=3, H=128, W=128, HID=64, NP=64, P=16, E=768, NH=4, dh=192
// Output = concat(patches (32*64*3*16*16), translate (32*64*2)), fp32.

#define PI_F 3.14159265358979323846f

typedef float f32x4 __attribute__((ext_vector_type(4)));
typedef short short8 __attribute__((ext_vector_type(8)));
typedef unsigned short us4 __attribute__((ext_vector_type(4)));
typedef __hip_bfloat16 bf16;

__device__ __forceinline__ void async16(const void* g, void* l) {
  __builtin_amdgcn_global_load_lds(
      (const __attribute__((address_space(1))) void*)g,
      (__attribute__((address_space(3))) void*)l, 16, 0, 0);
}

// ---------------- bf16 MFMA NT GEMM: C[M,N] = A[M,K] * Bw[N,K]^T ----------------
// 128x128 tile, BK=32, 256 threads (4 waves, 2x2 of 64x64), m97-style staging.
// Grid: x = (M/128)*(N/128) flattened with GROUP_M=8 supertile swizzle (XCD L2 reuse),
// z = split-K chunks.
// MODE 0: partial fp32 to Cout + z*M*N (no bias); MODE 1: fp32 + bias; MODE 2: bf16 + bias.
template <int MODE>
__global__ __launch_bounds__(256) void gemm_bf16(
    const unsigned short* __restrict__ A, const unsigned short* __restrict__ Bw,
    const float* __restrict__ bias, void* __restrict__ Cout,
    int M, int N, int K, int kchunk) {
  __shared__ unsigned short As[128 * 32];
  __shared__ unsigned short Bs[128 * 32];
  const int tid = threadIdx.x;
  // ---- swizzled tile coordinates ----
  const int bmT = M >> 7, bnT = N >> 7;
  int l = blockIdx.x;
  const int gsize = 8 * bnT;
  int gid = l / gsize;
  int rem = l - gid * gsize;
  int fm = gid * 8;
  int gsz = bmT - fm; if (gsz > 8) gsz = 8;
  const int bm = (fm + rem % gsz) << 7;
  const int bn = (rem / gsz) << 7;
  const int k0 = blockIdx.z * kchunk;
  const int wave = tid >> 6;
  const int lane = tid & 63;
  const int wm = (wave & 1) << 6, wn = (wave >> 1) << 6;
  const int r0 = tid >> 2;
  const int c0 = (tid & 3) << 3;
  const unsigned short* Ag0 = A + (size_t)(bm + r0) * K + k0 + c0;
  const unsigned short* Ag1 = Ag0 + (size_t)64 * K;
  const unsigned short* Bg0 = Bw + (size_t)(bn + r0) * K + k0 + c0;
  const unsigned short* Bg1 = Bg0 + (size_t)64 * K;
  unsigned short* Al = As + wave * 512;
  unsigned short* Bl = Bs + wave * 512;
  f32x4 acc[4][4] = {};
  const int fr = lane & 15;
  const int fk = (lane >> 4) << 3;
  for (int kt = 0; kt < kchunk; kt += 32) {
    async16(Ag0 + kt, Al);
    async16(Ag1 + kt, Al + 2048);
    async16(Bg0 + kt, Bl);
    async16(Bg1 + kt, Bl + 2048);
    __syncthreads();
    short8 af[4], bf[4];
    #pragma unroll
    for (int i = 0; i < 4; ++i)
      af[i] = *(const short8*)(As + ((wm + i * 16 + fr) << 5) + fk);
    #pragma unroll
    for (int i = 0; i < 4; ++i)
      bf[i] = *(const short8*)(Bs + ((wn + i * 16 + fr) << 5) + fk);
    #pragma unroll
    for (int mi = 0; mi < 4; ++mi)
      #pragma unroll
      for (int ni = 0; ni < 4; ++ni)
        acc[mi][ni] = __builtin_amdgcn_mfma_f32_16x16x32_bf16(af[mi], bf[ni], acc[mi][ni], 0, 0, 0);
    __syncthreads();
  }
  const int cr = (lane >> 4) << 2;
  const int cc = lane & 15;
  if (MODE == 0) {
    float* C = (float*)Cout + (size_t)blockIdx.z * M * N;
    #pragma unroll
    for (int mi = 0; mi < 4; ++mi)
      #pragma unroll
      for (int ni = 0; ni < 4; ++ni) {
        int col = bn + wn + ni * 16 + cc;
        #pragma unroll
        for (int r = 0; r < 4; ++r)
          C[(size_t)(bm + wm + mi * 16 + cr + r) * N + col] = acc[mi][ni][r];
      }
  } else {
    #pragma unroll
    for (int ni = 0; ni < 4; ++ni) {
      int col = bn + wn + ni * 16 + cc;
      float bv = bias[col];
      #pragma unroll
      for (int mi = 0; mi < 4; ++mi)
        #pragma unroll
        for (int r = 0; r < 4; ++r) {
          size_t idx = (size_t)(bm + wm + mi * 16 + cr + r) * N + col;
          float v = acc[mi][ni][r] + bv;
          if (MODE == 1) ((float*)Cout)[idx] = v;
          else ((bf16*)Cout)[idx] = __float2bfloat16(v);
        }
    }
  }
}

// ---------------- split-K reduce (vectorized x4): out_bf16 = act(sum_z part[z]+bias) -----
__global__ __launch_bounds__(256) void reduce_bias_k(
    const float* __restrict__ part, const float* __restrict__ bias,
    bf16* __restrict__ out, int MN, int N, int S, int relu) {
  int i = blockIdx.x * 256 + threadIdx.x;   // index of 4-elem group
  if (i >= (MN >> 2)) return;
  float4 s = ((const float4*)part)[i];
  for (int z = 1; z < S; ++z) {
    float4 q = *(const float4*)(part + (size_t)z * MN + i * 4);
    s.x += q.x; s.y += q.y; s.z += q.z; s.w += q.w;
  }
  int nb = (i * 4) % N;
  float4 bv = *(const float4*)(bias + nb);
  s.x += bv.x; s.y += bv.y; s.z += bv.z; s.w += bv.w;
  if (relu) {
    s.x = fmaxf(s.x, 0.f); s.y = fmaxf(s.y, 0.f);
    s.z = fmaxf(s.z, 0.f); s.w = fmaxf(s.w, 0.f);
  }
  bf16 vals[4] = {__float2bfloat16(s.x), __float2bfloat16(s.y),
                  __float2bfloat16(s.z), __float2bfloat16(s.w)};
  *(us4*)(out + (size_t)i * 4) = *(const us4*)vals;
}

// ---------------- fp32 -> bf16 weight conversion (1..3 tensors fused) ----------------
__global__ __launch_bounds__(256) void cvt3_k(
    const float* __restrict__ s0, bf16* __restrict__ d0, int n0,
    const float* __restrict__ s1, bf16* __restrict__ d1, int n1,
    const float* __restrict__ s2, bf16* __restrict__ d2, int n2) {
  int i = blockIdx.x * 256 + threadIdx.x;   // 4-elem group index
  const float* s; bf16* d; int j = i;
  if (j < n0) { s = s0; d = d0; }
  else {
    j -= n0;
    if (j < n1) { s = s1; d = d1; }
    else { j -= n1; if (j >= n2) return; s = s2; d = d2; }
  }
  float4 v = ((const float4*)s)[j];
  bf16 vals[4] = {__float2bfloat16(v.x), __float2bfloat16(v.y),
                  __float2bfloat16(v.z), __float2bfloat16(v.w)};
  *(us4*)(d + (size_t)j * 4) = *(const us4*)vals;
}

// ---------------- conv2 weight transpose: wcl[tap][oc][ic] bf16 ----------------
__global__ __launch_bounds__(256) void cvt_wcl_k(
    const float* __restrict__ w, bf16* __restrict__ wcl) {
  int i = blockIdx.x * 256 + threadIdx.x;   // 9*64*64 = 36864
  if (i >= 36864) return;
  int ic = i & 63, oc = (i >> 6) & 63, s = i >> 12;
  wcl[i] = __float2bfloat16(w[oc * 576 + ic * 9 + s]);
}

// ---------------- conv1 (fast): (32,3,128,128) -> bf16 (32,64,128,128), 3x3 SAME, ReLU ---
__global__ __launch_bounds__(256) void conv3x3_relu_c3_fast(
    const float* __restrict__ x, const float* __restrict__ w,
    const float* __restrict__ bias, bf16* __restrict__ out) {
  __shared__ float xs[3][4][132];
  __shared__ float wsm[3][9][64];
  const int tid = threadIdx.x;
  const int b = blockIdx.y;
  const int y0 = blockIdx.x * 2;
  const int xg = (tid & 15) * 8;
  const int row = (tid >> 4) & 1;
  const int oc0 = (tid >> 5) * 8;
  for (int i = tid; i < 3 * 4 * 132; i += 256) {
    int c = i % 132;
    int r = (i / 132) % 4;
    int ic = i / (132 * 4);
    int gy = y0 + r - 1;
    int gx = c - 1;
    float v = 0.f;
    if ((unsigned)gy < 128u && (unsigned)gx < 128u)
      v = x[((size_t)(b * 3 + ic) << 14) + gy * 128 + gx];
    xs[ic][r][c] = v;
  }
  for (int i = tid; i < 3 * 9 * 64; i += 256) {
    int oc = i & 63;
    int k = (i >> 6) % 9;
    int ic = i / (64 * 9);
    wsm[ic][k][oc] = w[oc * 27 + ic * 9 + k];
  }
  __syncthreads();
  float acc[8][8] = {};
  #pragma unroll
  for (int ic = 0; ic < 3; ++ic) {
    #pragma unroll
    for (int ky = 0; ky < 3; ++ky) {
      const float* rp = &xs[ic][row + ky][xg];
      float4 r0 = *(const float4*)(rp);
      float4 r1 = *(const float4*)(rp + 4);
      float4 r2 = *(const float4*)(rp + 8);
      float v[10] = {r0.x, r0.y, r0.z, r0.w, r1.x, r1.y, r1.z, r1.w, r2.x, r2.y};
      #pragma unroll
      for (int kx = 0; kx < 3; ++kx) {
        const float* wr = &wsm[ic][ky * 3 + kx][oc0];
        float4 w0 = *(const float4*)(wr);
        float4 w1 = *(const float4*)(wr + 4);
        float wv[8] = {w0.x, w0.y, w0.z, w0.w, w1.x, w1.y, w1.z, w1.w};
        #pragma unroll
        for (int o = 0; o < 8; ++o)
          #pragma unroll
          for (int p = 0; p < 8; ++p)
            acc[o][p] += wv[o] * v[p + kx];
      }
    }
  }
  #pragma unroll
  for (int o = 0; o < 8; ++o) {
    float bo = bias[oc0 + o];
    bf16 vals[8];
    #pragma unroll
    for (int p = 0; p < 8; ++p) vals[p] = __float2bfloat16(fmaxf(acc[o][p] + bo, 0.f));
    bf16* op = out + ((size_t)(b * 64 + oc0 + o) << 14) + (y0 + row) * 128 + xg;
    *(uint4*)op = *(const uint4*)vals;
  }
}

// ---------------- maxpool 2x2 -> channels-last padded xp[b][66][66][64] bf16 -------------
__global__ __launch_bounds__(256) void maxpool_cl(
    const bf16* __restrict__ y1, bf16* __restrict__ xp) {
  int wave = threadIdx.x >> 6;
  int lane = threadIdx.x & 63;
  int cell = blockIdx.x * 4 + wave;
  int b = blockIdx.y;
  int yp = cell / 66, xq = cell % 66;
  bf16* dst = xp + (((size_t)b * 66 + yp) * 66 + xq) * 64 + lane;
  if (yp == 0 || yp == 65 || xq == 0 || xq == 65) {
    *dst = __float2bfloat16(0.f);
    return;
  }
  int py = yp - 1, px = xq - 1;
  const bf16* sp = y1 + ((size_t)(b * 64 + lane) << 14) + (py * 2) * 128 + px * 2;
  float a = __bfloat162float(sp[0]), bq = __bfloat162float(sp[1]);
  float c = __bfloat162float(sp[128]), d = __bfloat162float(sp[129]);
  *dst = __float2bfloat16(fmaxf(fmaxf(a, bq), fmaxf(c, d)));
}

// ---------------- conv2 MFMA: xp (padded CL) -> f3[b][oc][4096] bf16, bias+ReLU ----------
__global__ __launch_bounds__(256) void conv2_mfma(
    const bf16* __restrict__ xp, const bf16* __restrict__ wcl,
    const float* __restrict__ bias, bf16* __restrict__ f3) {
  __shared__ unsigned short As[128 * 32];
  __shared__ unsigned short Bs[64 * 32];
  const int tid = threadIdx.x;
  const int b = blockIdx.y;
  const int y0 = blockIdx.x * 2;
  const int wave = tid >> 6;
  const int lane = tid & 63;
  const int wm = (wave & 1) << 6;
  const int wn = (wave >> 1) << 5;
  const char* xpB = (const char*)(xp + (size_t)b * 66 * 66 * 64);
  const char* wclB = (const char*)wcl;
  const int sr = tid >> 2;
  const int soff = (tid & 3) << 4;
  unsigned short* Al = As + wave * 512;
  unsigned short* Bl = Bs + wave * 512;
  f32x4 acc[4][2] = {};
  const int fr = lane & 15;
  const int fk = (lane >> 4) << 3;
  for (int tap = 0; tap < 9; ++tap) {
    int dy = tap / 3, dx = tap % 3;
    const char* arow0 = xpB + (((y0 + dy) * 66 + dx) << 7);
    const char* brow = wclB + (tap << 13);
    #pragma unroll
    for (int ch = 0; ch < 2; ++ch) {
      int coff = (ch << 6) + soff;
      async16(arow0 + sr * 128 + coff, Al);
      async16(arow0 + 66 * 128 + sr * 128 + coff, Al + 2048);
      async16(brow + sr * 128 + coff, Bl);
      __syncthreads();
      short8 af[4], bf[2];
      #pragma unroll
      for (int i = 0; i < 4; ++i)
        af[i] = *(const short8*)(As + ((wm + i * 16 + fr) << 5) + fk);
      #pragma unroll
      for (int i = 0; i < 2; ++i)
        bf[i] = *(const short8*)(Bs + ((wn + i * 16 + fr) << 5) + fk);
      #pragma unroll
      for (int mi = 0; mi < 4; ++mi)
        #pragma unroll
        for (int ni = 0; ni < 2; ++ni)
          acc[mi][ni] = __builtin_amdgcn_mfma_f32_16x16x32_bf16(af[mi], bf[ni], acc[mi][ni], 0, 0, 0);
      __syncthreads();
    }
  }
  const int cr = (lane >> 4) << 2;
  const int cc = lane & 15;
  #pragma unroll
  for (int ni = 0; ni < 2; ++ni) {
    int oc = wn + ni * 16 + cc;
    float bv = bias[oc];
    #pragma unroll
    for (int mi = 0; mi < 4; ++mi) {
      int pxb = wm + mi * 16 + cr;
      int y = y0 + (pxb >> 6), xb = pxb & 63;
      bf16 vals[4];
      #pragma unroll
      for (int r = 0; r < 4; ++r)
        vals[r] = __float2bfloat16(fmaxf(acc[mi][ni][r] + bv, 0.f));
      bf16* op = f3 + (((size_t)(b * 64 + oc)) << 12) + y * 64 + xb;
      *(us4*)op = *(const us4*)vals;
    }
  }
}

// ---------------- attention: scores + softmax (fp32 qkv) ----------------
__global__ __launch_bounds__(64) void attn_scores(
    const float* __restrict__ qkv, float* __restrict__ p, float scale) {
  int tq = blockIdx.x, h = blockIdx.y, b = blockIdx.z;
  int lane = threadIdx.x;
  __shared__ float qrow[192];
  const float* qp = qkv + ((size_t)(b * 64 + tq)) * 2304 + h * 192;
  for (int d = lane; d < 192; d += 64) qrow[d] = qp[d];
  __syncthreads();
  const float* kp = qkv + ((size_t)(b * 64 + lane)) * 2304 + 768 + h * 192;
  float s = 0.f;
  for (int d = 0; d < 192; ++d) s += qrow[d] * kp[d];
  s *= scale;
  float m = s;
  for (int off = 32; off; off >>= 1) m = fmaxf(m, __shfl_xor(m, off));
  float e = expf(s - m);
  float sum = e;
  for (int off = 32; off; off >>= 1) sum += __shfl_xor(sum, off);
  p[(((size_t)b * 4 + h) * 64 + tq) * 64 + lane] = e / sum;
}

// ---------------- attention: o = p @ v, bf16 out ----------------
__global__ __launch_bounds__(256) void attn_o(
    const float* __restrict__ p, const float* __restrict__ qkv, bf16* __restrict__ o) {
  size_t tid = (size_t)blockIdx.x * 256 + threadIdx.x;
  if (tid >= (size_t)32 * 64 * 768) return;
  int e = (int)(tid % 768);
  int tq = (int)((tid / 768) % 64);
  int b = (int)(tid / (768 * 64));
  int h = e / 192;
  const float* pp = p + (((size_t)b * 4 + h) * 64 + tq) * 64;
  const float* vp = qkv + (size_t)b * 64 * 2304 + 1536 + e;
  float acc = 0.f;
  for (int tk = 0; tk < 64; ++tk) acc += pp[tk] * vp[(size_t)tk * 2304];
  o[tid] = __float2bfloat16(acc);
}

// ---------------- fc2: one wave per (m,n), shuffle-reduce dot ----------------
__global__ __launch_bounds__(256) void fc2_wave(
    const bf16* __restrict__ A, const float* __restrict__ Bw,
    const float* __restrict__ bias, float* __restrict__ C, int K) {
  int m = blockIdx.x;
  int n = threadIdx.x >> 6;
  int lane = threadIdx.x & 63;
  const bf16* a = A + (size_t)m * K;
  const float* bb = Bw + (size_t)n * K;
  float acc = 0.f;
  for (int k = lane; k < K; k += 64)
    acc += __bfloat162float(a[k]) * bb[k];
  for (int off = 32; off; off >>= 1) acc += __shfl_xor(acc, off);
  if (lane == 0) C[m * 4 + n] = acc + bias[n];
}

// ---------------- transform params + translate output ----------------
__global__ __launch_bounds__(64) void params_k(
    const float* __restrict__ tp, float* __restrict__ par, float* __restrict__ trans_out) {
  int m = blockIdx.x * 64 + threadIdx.x;
  if (m >= 2048) return;
  float t0 = tp[m * 4 + 0], t1 = tp[m * 4 + 1], t2 = tp[m * 4 + 2], t3 = tp[m * 4 + 3];
  float trx = tanhf(t0), tryy = tanhf(t1);
  float s = (1.f / (1.f + expf(-t2))) * 0.3f;
  float rot = tanhf(t3) * PI_F;
  float c = cosf(rot), sn = sinf(rot);
  float x_ext = fminf(s * fabsf(c) + s * fabsf(sn), 1.f);
  float y_ext = fminf(s * fabsf(sn) + s * fabsf(c), 1.f);
  float tx = trx * (1.f - x_ext);
  float ty = tryy * (1.f - y_ext);
  par[m * 8 + 0] = s * c;
  par[m * 8 + 1] = -s * sn;
  par[m * 8 + 2] = s * sn;
  par[m * 8 + 3] = s * c;
  par[m * 8 + 4] = tx;
  par[m * 8 + 5] = ty;
  trans_out[m * 2 + 0] = tx;
  trans_out[m * 2 + 1] = ty;
}

// ---------------- bilinear grid sample (fp32 x) ----------------
__global__ __launch_bounds__(256) void sample_k(
    const float* __restrict__ x, const float* __restrict__ par, float* __restrict__ out) {
  int tid = blockIdx.x * 256 + threadIdx.x;
  if (tid >= 32 * 64 * 3 * 256) return;
  int pj = tid & 15, pi = (tid >> 4) & 15;
  int c = (tid >> 8) % 3;
  int bp = tid / 768;
  int b = bp >> 6;
  const float* pp = par + bp * 8;
  float ta = pp[0], tb = pp[1], tc = pp[2], td = pp[3], tx = pp[4], ty = pp[5];
  float bj = (2.f * pj + 1.f) / 16.f - 1.f;
  float bi = (2.f * pi + 1.f) / 16.f - 1.f;
  float gx = ta * bj + tb * bi + tx;
  float gy = tc * bj + td * bi + ty;
  float xs = ((gx + 1.f) * 128.f - 1.f) * 0.5f;
  float ys = ((gy + 1.f) * 128.f - 1.f) * 0.5f;
  float x0f = floorf(xs), y0f = floorf(ys);
  float wx = xs - x0f, wy = ys - y0f;
  int x0 = (int)x0f, y0 = (int)y0f, x1 = x0 + 1, y1 = y0 + 1;
  const float* img = x + ((size_t)b * 3 + c) * 16384;
  auto g = [&](int yi, int xi) -> float {
    bool v = (xi >= 0) && (xi < 128) && (yi >= 0) && (yi < 128);
    int yc = yi < 0 ? 0 : (yi > 127 ? 127 : yi);
    int xc = xi < 0 ? 0 : (xi > 127 ? 127 : xi);
    float val = img[yc * 128 + xc];
    return v ? val : 0.f;
  };
  float v00 = g(y0, x0), v01 = g(y0, x1), v10 = g(y1, x0), v11 = g(y1, x1);
  out[tid] = v00 * (1.f - wx) * (1.f - wy) + v01 * wx * (1.f - wy) +
             v10 * (1.f - wx) * wy + v11 * wx * wy;
}

extern "C" void kernel_launch(void* const* d_in, const int* in_sizes, int n_in,
                              void* d_out, int out_size, void* d_ws, size_t ws_size,
                              hipStream_t stream) {
  const float* x        = (const float*)d_in[0];
  const float* conv1_w  = (const float*)d_in[1];
  const float* conv1_b  = (const float*)d_in[2];
  const float* a1_in_w  = (const float*)d_in[3];
  const float* a1_in_b  = (const float*)d_in[4];
  const float* a1_qkv_w = (const float*)d_in[5];
  const float* a1_qkv_b = (const float*)d_in[6];
  const float* a1_out_w = (const float*)d_in[7];
  const float* a1_out_b = (const float*)d_in[8];
  const float* a1_proj_w = (const float*)d_in[9];
  const float* a1_proj_b = (const float*)d_in[10];
  const float* conv2_w  = (const float*)d_in[11];
  const float* conv2_b  = (const float*)d_in[12];
  const float* a2_in_w  = (const float*)d_in[13];
  const float* a2_in_b  = (const float*)d_in[14];
  const float* a2_qkv_w = (const float*)d_in[15];
  const float* a2_qkv_b = (const float*)d_in[16];
  const float* a2_out_w = (const float*)d_in[17];
  const float* a2_out_b = (const float*)d_in[18];
  const float* a2_proj_w = (const float*)d_in[19];
  const float* a2_proj_b = (const float*)d_in[20];
  const float* fc1_w    = (const float*)d_in[21];
  const float* fc1_b    = (const float*)d_in[22];
  const float* fc2_w    = (const float*)d_in[23];
  const float* fc2_b    = (const float*)d_in[24];
  float* out = (float*)d_out;

  char* ws = (char*)d_ws;
  bf16*  f1   = (bf16*)(ws + 0);            // conv1 out / proj1 out (y1)
  bf16*  y1   = f1;
  bf16*  f3   = (bf16*)(ws + 0);            // conv2 out (y1 dead)
  bf16*  h1   = (bf16*)(ws + 33554432);
  float* part = (float*)(ws + 83886080);    // split-K partials (50 MB)
  bf16*  xp   = (bf16*)(ws + 83886080);     // padded CL pool out (xp ends before 101.7M)
  bf16*  t    = (bf16*)(ws + 134217728);
  float* qkv  = (float*)(ws + 137363456);
  float* p    = (float*)(ws + 156237824);
  bf16*  o    = (bf16*)(ws + 158334976);
  bf16*  ao   = (bf16*)(ws + 161480704);
  bf16*  y2   = (bf16*)(ws + 164626432);    // also hosts Wq/Wo before proj2 writes it
  float* tp   = (float*)(ws + 181403648);
  float* par  = (float*)(ws + 181436416);
  bf16*  W    = (bf16*)(ws + 181501952);    // 25.2 MB weight scratch (reused)
  bf16*  wcl  = W;                          // conv2 weights [tap][oc][ic]
  bf16*  Wq   = (bf16*)(ws + 164626432);            // qkv_w bf16 (3.54 MB), in y2 region
  bf16*  Wo   = (bf16*)(ws + 164626432 + 3538944);  // out_w bf16 (1.18 MB)

  const unsigned short* Wu = (const unsigned short*)W;
  const unsigned short* Wqu = (const unsigned short*)Wq;
  const unsigned short* Wou = (const unsigned short*)Wo;
  const float scale = 0.07216878364870323f; // 1/sqrt(192)

  // quad-group counts (elements/4) for fused converts
  const int n_in1 = 768 * 16384 / 4, n_qkv = 2304 * 768 / 4, n_out = 768 * 768 / 4;
  const int n_in2 = 768 * 4096 / 4;
  const int n_proj1 = 16384 * 768 / 4, n_proj2 = 4096 * 768 / 4, n_fc1 = 2048 * 4096 / 4;

  conv3x3_relu_c3_fast<<<dim3(64, 32), 256, 0, stream>>>(x, conv1_w, conv1_b, f1);
  // stage-1 weights: in_w -> W, qkv_w -> Wq, out_w -> Wo (one launch)
  cvt3_k<<<(n_in1 + n_qkv + n_out + 255) / 256, 256, 0, stream>>>(
      a1_in_w, W, n_in1, a1_qkv_w, Wq, n_qkv, a1_out_w, Wo, n_out);
  gemm_bf16<0><<<dim3(96, 1, 8), 256, 0, stream>>>((const unsigned short*)f1, Wu, nullptr, part, 2048, 768, 16384, 2048);
  reduce_bias_k<<<1536, 256, 0, stream>>>(part, a1_in_b, t, 2048 * 768, 768, 8, 0);
  gemm_bf16<1><<<dim3(288, 1, 1), 256, 0, stream>>>((const unsigned short*)t, Wqu, a1_qkv_b, qkv, 2048, 2304, 768, 768);
  attn_scores<<<dim3(64, 4, 32), 64, 0, stream>>>(qkv, p, scale);
  attn_o<<<6144, 256, 0, stream>>>(p, qkv, o);
  gemm_bf16<0><<<dim3(96, 1, 3), 256, 0, stream>>>((const unsigned short*)o, Wou, nullptr, part, 2048, 768, 768, 256);
  reduce_bias_k<<<1536, 256, 0, stream>>>(part, a1_out_b, ao, 2048 * 768, 768, 3, 0);
  cvt3_k<<<(n_proj1 + 255) / 256, 256, 0, stream>>>(
      a1_proj_w, W, n_proj1, nullptr, nullptr, 0, nullptr, nullptr, 0);
  gemm_bf16<2><<<dim3(2048, 1, 1), 256, 0, stream>>>((const unsigned short*)ao, Wu, a1_proj_b, y1, 2048, 16384, 768, 768);
  // conv2 prep
  cvt_wcl_k<<<144, 256, 0, stream>>>(conv2_w, wcl);
  maxpool_cl<<<dim3(1089, 32), 256, 0, stream>>>(y1, xp);
  conv2_mfma<<<dim3(32, 32), 256, 0, stream>>>(xp, wcl, conv2_b, f3);
  // stage-2 weights
  cvt3_k<<<(n_in2 + n_qkv + n_out + 255) / 256, 256, 0, stream>>>(
      a2_in_w, W, n_in2, a2_qkv_w, Wq, n_qkv, a2_out_w, Wo, n_out);
  gemm_bf16<0><<<dim3(96, 1, 4), 256, 0, stream>>>((const unsigned short*)f3, Wu, nullptr, part, 2048, 768, 4096, 1024);
  reduce_bias_k<<<1536, 256, 0, stream>>>(part, a2_in_b, t, 2048 * 768, 768, 4, 0);
  gemm_bf16<1><<<dim3(288, 1, 1), 256, 0, stream>>>((const unsigned short*)t, Wqu, a2_qkv_b, qkv, 2048, 2304, 768, 768);
  attn_scores<<<dim3(64, 4, 32), 64, 0, stream>>>(qkv, p, scale);
  attn_o<<<6144, 256, 0, stream>>>(p, qkv, o);
  gemm_bf16<0><<<dim3(96, 1, 3), 256, 0, stream>>>((const unsigned short*)o, Wou, nullptr, part, 2048, 768, 768, 256);
  reduce_bias_k<<<1536, 256, 0, stream>>>(part, a2_out_b, ao, 2048 * 768, 768, 3, 0);
  cvt3_k<<<(n_proj2 + 255) / 256, 256, 0, stream>>>(
      a2_proj_w, W, n_proj2, nullptr, nullptr, 0, nullptr, nullptr, 0);
  gemm_bf16<2><<<dim3(512, 1, 1), 256, 0, stream>>>((const unsigned short*)ao, Wu, a2_proj_b, y2, 2048, 4096, 768, 768);
  cvt3_k<<<(n_fc1 + 255) / 256, 256, 0, stream>>>(
      fc1_w, W, n_fc1, nullptr, nullptr, 0, nullptr, nullptr, 0);
  gemm_bf16<0><<<dim3(256, 1, 2), 256, 0, stream>>>((const unsigned short*)y2, Wu, nullptr, part, 2048, 2048, 4096, 2048);
  reduce_bias_k<<<4096, 256, 0, stream>>>(part, fc1_b, h1, 2048 * 2048, 2048, 2, 1);
  fc2_wave<<<2048, 256, 0, stream>>>(h1, fc2_w, fc2_b, tp, 2048);
  params_k<<<32, 64, 0, stream>>>(tp, par, out + 1572864);
  sample_k<<<6144, 256, 0, stream>>>(x, par, out);
}

// Round 7
// 773.694 us; speedup vs baseline: 6.4364x; 1.1663x over previous
//
#include <hip/hip_runtime.h>
#include <hip/hip_bf16.h>
#include <math.h>

// Shapes (fixed): B=32, C=3, H=128, W=128, HID=64, NP=64, P=16, E=768, NH=4, dh=192
// Output = concat(patches (32*64*3*16*16), translate (32*64*2)), fp32.

#define PI_F 3.14159265358979323846f

typedef float f32x4 __attribute__((ext_vector_type(4)));
typedef short short8 __attribute__((ext_vector_type(8)));
typedef unsigned short us4 __attribute__((ext_vector_type(4)));
typedef __hip_bfloat16 bf16;

__device__ __forceinline__ void async16(const void* g, void* l) {
  __builtin_amdgcn_global_load_lds(
      (const __attribute__((address_space(1))) void*)g,
      (__attribute__((address_space(3))) void*)l, 16, 0, 0);
}

// ---------------- bf16 MFMA NT GEMM: C[M,N] = A[M,K] * Bw[N,K]^T ----------------
// 128x128 tile, BK=32, 256 threads (4 waves, 2x2 of 64x64), m97-style staging.
// Grid: x = (M/128)*(N/128) flattened with GROUP_M=8 supertile swizzle, z = split-K.
// MODE 0: partial fp32 to Cout + z*M*N (no bias); MODE 1: fp32 + bias; MODE 2: bf16 + bias.
template <int MODE>
__global__ __launch_bounds__(256) void gemm_bf16(
    const unsigned short* __restrict__ A, const unsigned short* __restrict__ Bw,
    const float* __restrict__ bias, void* __restrict__ Cout,
    int M, int N, int K, int kchunk) {
  __shared__ unsigned short As[128 * 32];
  __shared__ unsigned short Bs[128 * 32];
  const int tid = threadIdx.x;
  const int bmT = M >> 7, bnT = N >> 7;
  int l = blockIdx.x;
  const int gsize = 8 * bnT;
  int gid = l / gsize;
  int rem = l - gid * gsize;
  int fm = gid * 8;
  int gsz = bmT - fm; if (gsz > 8) gsz = 8;
  const int bm = (fm + rem % gsz) << 7;
  const int bn = (rem / gsz) << 7;
  const int k0 = blockIdx.z * kchunk;
  const int wave = tid >> 6;
  const int lane = tid & 63;
  const int wm = (wave & 1) << 6, wn = (wave >> 1) << 6;
  const int r0 = tid >> 2;
  const int c0 = (tid & 3) << 3;
  const unsigned short* Ag0 = A + (size_t)(bm + r0) * K + k0 + c0;
  const unsigned short* Ag1 = Ag0 + (size_t)64 * K;
  const unsigned short* Bg0 = Bw + (size_t)(bn + r0) * K + k0 + c0;
  const unsigned short* Bg1 = Bg0 + (size_t)64 * K;
  unsigned short* Al = As + wave * 512;
  unsigned short* Bl = Bs + wave * 512;
  f32x4 acc[4][4] = {};
  const int fr = lane & 15;
  const int fk = (lane >> 4) << 3;
  for (int kt = 0; kt < kchunk; kt += 32) {
    async16(Ag0 + kt, Al);
    async16(Ag1 + kt, Al + 2048);
    async16(Bg0 + kt, Bl);
    async16(Bg1 + kt, Bl + 2048);
    __syncthreads();
    short8 af[4], bf[4];
    #pragma unroll
    for (int i = 0; i < 4; ++i)
      af[i] = *(const short8*)(As + ((wm + i * 16 + fr) << 5) + fk);
    #pragma unroll
    for (int i = 0; i < 4; ++i)
      bf[i] = *(const short8*)(Bs + ((wn + i * 16 + fr) << 5) + fk);
    #pragma unroll
    for (int mi = 0; mi < 4; ++mi)
      #pragma unroll
      for (int ni = 0; ni < 4; ++ni)
        acc[mi][ni] = __builtin_amdgcn_mfma_f32_16x16x32_bf16(af[mi], bf[ni], acc[mi][ni], 0, 0, 0);
    __syncthreads();
  }
  const int cr = (lane >> 4) << 2;
  const int cc = lane & 15;
  if (MODE == 0) {
    float* C = (float*)Cout + (size_t)blockIdx.z * M * N;
    #pragma unroll
    for (int mi = 0; mi < 4; ++mi)
      #pragma unroll
      for (int ni = 0; ni < 4; ++ni) {
        int col = bn + wn + ni * 16 + cc;
        #pragma unroll
        for (int r = 0; r < 4; ++r)
          C[(size_t)(bm + wm + mi * 16 + cr + r) * N + col] = acc[mi][ni][r];
      }
  } else {
    #pragma unroll
    for (int ni = 0; ni < 4; ++ni) {
      int col = bn + wn + ni * 16 + cc;
      float bv = bias[col];
      #pragma unroll
      for (int mi = 0; mi < 4; ++mi)
        #pragma unroll
        for (int r = 0; r < 4; ++r) {
          size_t idx = (size_t)(bm + wm + mi * 16 + cr + r) * N + col;
          float v = acc[mi][ni][r] + bv;
          if (MODE == 1) ((float*)Cout)[idx] = v;
          else ((bf16*)Cout)[idx] = __float2bfloat16(v);
        }
    }
  }
}

// ---------------- split-K reduce (vectorized x4): out_bf16 = act(sum_z part[z]+bias) -----
__global__ __launch_bounds__(256) void reduce_bias_k(
    const float* __restrict__ part, const float* __restrict__ bias,
    bf16* __restrict__ out, int MN, int N, int S, int relu) {
  int i = blockIdx.x * 256 + threadIdx.x;
  if (i >= (MN >> 2)) return;
  float4 s = ((const float4*)part)[i];
  for (int z = 1; z < S; ++z) {
    float4 q = *(const float4*)(part + (size_t)z * MN + i * 4);
    s.x += q.x; s.y += q.y; s.z += q.z; s.w += q.w;
  }
  int nb = (i * 4) % N;
  float4 bv = *(const float4*)(bias + nb);
  s.x += bv.x; s.y += bv.y; s.z += bv.z; s.w += bv.w;
  if (relu) {
    s.x = fmaxf(s.x, 0.f); s.y = fmaxf(s.y, 0.f);
    s.z = fmaxf(s.z, 0.f); s.w = fmaxf(s.w, 0.f);
  }
  bf16 vals[4] = {__float2bfloat16(s.x), __float2bfloat16(s.y),
                  __float2bfloat16(s.z), __float2bfloat16(s.w)};
  *(us4*)(out + (size_t)i * 4) = *(const us4*)vals;
}

// ---------------- fp32 -> bf16 weight conversion (1..3 tensors fused) ----------------
__global__ __launch_bounds__(256) void cvt3_k(
    const float* __restrict__ s0, bf16* __restrict__ d0, int n0,
    const float* __restrict__ s1, bf16* __restrict__ d1, int n1,
    const float* __restrict__ s2, bf16* __restrict__ d2, int n2) {
  int i = blockIdx.x * 256 + threadIdx.x;
  const float* s; bf16* d; int j = i;
  if (j < n0) { s = s0; d = d0; }
  else {
    j -= n0;
    if (j < n1) { s = s1; d = d1; }
    else { j -= n1; if (j >= n2) return; s = s2; d = d2; }
  }
  float4 v = ((const float4*)s)[j];
  bf16 vals[4] = {__float2bfloat16(v.x), __float2bfloat16(v.y),
                  __float2bfloat16(v.z), __float2bfloat16(v.w)};
  *(us4*)(d + (size_t)j * 4) = *(const us4*)vals;
}

// ---------------- conv2 weight transpose: wcl[tap][oc][ic] bf16 ----------------
__global__ __launch_bounds__(256) void cvt_wcl_k(
    const float* __restrict__ w, bf16* __restrict__ wcl) {
  int i = blockIdx.x * 256 + threadIdx.x;
  if (i >= 36864) return;
  int ic = i & 63, oc = (i >> 6) & 63, s = i >> 12;
  wcl[i] = __float2bfloat16(w[oc * 576 + ic * 9 + s]);
}

// ---------------- conv1 (fast): (32,3,128,128) -> bf16 (32,64,128,128), 3x3 SAME, ReLU ---
__global__ __launch_bounds__(256) void conv3x3_relu_c3_fast(
    const float* __restrict__ x, const float* __restrict__ w,
    const float* __restrict__ bias, bf16* __restrict__ out) {
  __shared__ float xs[3][4][132];
  __shared__ float wsm[3][9][64];
  const int tid = threadIdx.x;
  const int b = blockIdx.y;
  const int y0 = blockIdx.x * 2;
  const int xg = (tid & 15) * 8;
  const int row = (tid >> 4) & 1;
  const int oc0 = (tid >> 5) * 8;
  for (int i = tid; i < 3 * 4 * 132; i += 256) {
    int c = i % 132;
    int r = (i / 132) % 4;
    int ic = i / (132 * 4);
    int gy = y0 + r - 1;
    int gx = c - 1;
    float v = 0.f;
    if ((unsigned)gy < 128u && (unsigned)gx < 128u)
      v = x[((size_t)(b * 3 + ic) << 14) + gy * 128 + gx];
    xs[ic][r][c] = v;
  }
  for (int i = tid; i < 3 * 9 * 64; i += 256) {
    int oc = i & 63;
    int k = (i >> 6) % 9;
    int ic = i / (64 * 9);
    wsm[ic][k][oc] = w[oc * 27 + ic * 9 + k];
  }
  __syncthreads();
  float acc[8][8] = {};
  #pragma unroll
  for (int ic = 0; ic < 3; ++ic) {
    #pragma unroll
    for (int ky = 0; ky < 3; ++ky) {
      const float* rp = &xs[ic][row + ky][xg];
      float4 r0 = *(const float4*)(rp);
      float4 r1 = *(const float4*)(rp + 4);
      float4 r2 = *(const float4*)(rp + 8);
      float v[10] = {r0.x, r0.y, r0.z, r0.w, r1.x, r1.y, r1.z, r1.w, r2.x, r2.y};
      #pragma unroll
      for (int kx = 0; kx < 3; ++kx) {
        const float* wr = &wsm[ic][ky * 3 + kx][oc0];
        float4 w0 = *(const float4*)(wr);
        float4 w1 = *(const float4*)(wr + 4);
        float wv[8] = {w0.x, w0.y, w0.z, w0.w, w1.x, w1.y, w1.z, w1.w};
        #pragma unroll
        for (int o = 0; o < 8; ++o)
          #pragma unroll
          for (int p = 0; p < 8; ++p)
            acc[o][p] += wv[o] * v[p + kx];
      }
    }
  }
  #pragma unroll
  for (int o = 0; o < 8; ++o) {
    float bo = bias[oc0 + o];
    bf16 vals[8];
    #pragma unroll
    for (int p = 0; p < 8; ++p) vals[p] = __float2bfloat16(fmaxf(acc[o][p] + bo, 0.f));
    bf16* op = out + ((size_t)(b * 64 + oc0 + o) << 14) + (y0 + row) * 128 + xg;
    *(uint4*)op = *(const uint4*)vals;
  }
}

// ---------------- maxpool 2x2 -> channels-last padded xp[b][66][66][64] bf16 -------------
__global__ __launch_bounds__(256) void maxpool_cl(
    const bf16* __restrict__ y1, bf16* __restrict__ xp) {
  int wave = threadIdx.x >> 6;
  int lane = threadIdx.x & 63;
  int cell = blockIdx.x * 4 + wave;
  int b = blockIdx.y;
  int yp = cell / 66, xq = cell % 66;
  bf16* dst = xp + (((size_t)b * 66 + yp) * 66 + xq) * 64 + lane;
  if (yp == 0 || yp == 65 || xq == 0 || xq == 65) {
    *dst = __float2bfloat16(0.f);
    return;
  }
  int py = yp - 1, px = xq - 1;
  const bf16* sp = y1 + ((size_t)(b * 64 + lane) << 14) + (py * 2) * 128 + px * 2;
  float a = __bfloat162float(sp[0]), bq = __bfloat162float(sp[1]);
  float c = __bfloat162float(sp[128]), d = __bfloat162float(sp[129]);
  *dst = __float2bfloat16(fmaxf(fmaxf(a, bq), fmaxf(c, d)));
}

// ---------------- conv2 MFMA: xp (padded CL) -> f3[b][oc][4096] bf16, bias+ReLU ----------
__global__ __launch_bounds__(256) void conv2_mfma(
    const bf16* __restrict__ xp, const bf16* __restrict__ wcl,
    const float* __restrict__ bias, bf16* __restrict__ f3) {
  __shared__ unsigned short As[128 * 32];
  __shared__ unsigned short Bs[64 * 32];
  const int tid = threadIdx.x;
  const int b = blockIdx.y;
  const int y0 = blockIdx.x * 2;
  const int wave = tid >> 6;
  const int lane = tid & 63;
  const int wm = (wave & 1) << 6;
  const int wn = (wave >> 1) << 5;
  const char* xpB = (const char*)(xp + (size_t)b * 66 * 66 * 64);
  const char* wclB = (const char*)wcl;
  const int sr = tid >> 2;
  const int soff = (tid & 3) << 4;
  unsigned short* Al = As + wave * 512;
  unsigned short* Bl = Bs + wave * 512;
  f32x4 acc[4][2] = {};
  const int fr = lane & 15;
  const int fk = (lane >> 4) << 3;
  for (int tap = 0; tap < 9; ++tap) {
    int dy = tap / 3, dx = tap % 3;
    const char* arow0 = xpB + (((y0 + dy) * 66 + dx) << 7);
    const char* brow = wclB + (tap << 13);
    #pragma unroll
    for (int ch = 0; ch < 2; ++ch) {
      int coff = (ch << 6) + soff;
      async16(arow0 + sr * 128 + coff, Al);
      async16(arow0 + 66 * 128 + sr * 128 + coff, Al + 2048);
      async16(brow + sr * 128 + coff, Bl);
      __syncthreads();
      short8 af[4], bf[2];
      #pragma unroll
      for (int i = 0; i < 4; ++i)
        af[i] = *(const short8*)(As + ((wm + i * 16 + fr) << 5) + fk);
      #pragma unroll
      for (int i = 0; i < 2; ++i)
        bf[i] = *(const short8*)(Bs + ((wn + i * 16 + fr) << 5) + fk);
      #pragma unroll
      for (int mi = 0; mi < 4; ++mi)
        #pragma unroll
        for (int ni = 0; ni < 2; ++ni)
          acc[mi][ni] = __builtin_amdgcn_mfma_f32_16x16x32_bf16(af[mi], bf[ni], acc[mi][ni], 0, 0, 0);
      __syncthreads();
    }
  }
  const int cr = (lane >> 4) << 2;
  const int cc = lane & 15;
  #pragma unroll
  for (int ni = 0; ni < 2; ++ni) {
    int oc = wn + ni * 16 + cc;
    float bv = bias[oc];
    #pragma unroll
    for (int mi = 0; mi < 4; ++mi) {
      int pxb = wm + mi * 16 + cr;
      int y = y0 + (pxb >> 6), xb = pxb & 63;
      bf16 vals[4];
      #pragma unroll
      for (int r = 0; r < 4; ++r)
        vals[r] = __float2bfloat16(fmaxf(acc[mi][ni][r] + bv, 0.f));
      bf16* op = f3 + (((size_t)(b * 64 + oc)) << 12) + y * 64 + xb;
      *(us4*)op = *(const us4*)vals;
    }
  }
}

// ---------------- fused attention: one block per (b,h), S=64, dh=192, bf16 MFMA ----------
// qkv: [2048][2304] bf16 (q|k|v). o: [2048][768] bf16.
__global__ __launch_bounds__(256) void attn_fused(
    const bf16* __restrict__ qkv, bf16* __restrict__ o, float scale) {
  __shared__ unsigned short Qs[64][216];   // row stride 432 B: 16B-aligned, 2-way banks
  __shared__ unsigned short Ks[64][216];
  __shared__ unsigned short Vt[192][72];   // [dim][key], stride 144 B
  __shared__ unsigned short Ps[64][72];    // P in A-layout rows
  const int tid = threadIdx.x;
  const int b = blockIdx.x >> 2, h = blockIdx.x & 3;
  const unsigned short* base = (const unsigned short*)qkv + (size_t)b * 64 * 2304 + h * 192;
  // stage Q,K vectorized; V transposed (scalar writes)
  for (int c = tid; c < 1536; c += 256) {
    int tok = c / 24, idx = (c % 24) * 8;
    const unsigned short* rp = base + (size_t)tok * 2304 + idx;
    short8 qv = *(const short8*)(rp);
    short8 kv = *(const short8*)(rp + 768);
    short8 vv = *(const short8*)(rp + 1536);
    *(short8*)&Qs[tok][idx] = qv;
    *(short8*)&Ks[tok][idx] = kv;
    #pragma unroll
    for (int j = 0; j < 8; ++j) Vt[idx + j][tok] = (unsigned short)vv[j];
  }
  __syncthreads();
  const int wave = tid >> 6, lane = tid & 63;
  const int fr = lane & 15;
  const int fk = (lane >> 4) << 3;
  // QK^T: wave handles q rows 16w..16w+15 x all 64 keys
  f32x4 accs[4] = {};
  #pragma unroll
  for (int kk = 0; kk < 6; ++kk) {
    short8 aq = *(const short8*)&Qs[wave * 16 + fr][kk * 32 + fk];
    #pragma unroll
    for (int n = 0; n < 4; ++n) {
      short8 bk = *(const short8*)&Ks[n * 16 + fr][kk * 32 + fk];
      accs[n] = __builtin_amdgcn_mfma_f32_16x16x32_bf16(aq, bk, accs[n], 0, 0, 0);
    }
  }
  // softmax per q row (row = wave*16 + (lane>>4)*4 + r, cols spread over 16 lanes x 4 n)
  const int cr = (lane >> 4) << 2;
  const int cc = lane & 15;
  #pragma unroll
  for (int r = 0; r < 4; ++r) {
    float v0 = accs[0][r] * scale, v1 = accs[1][r] * scale;
    float v2 = accs[2][r] * scale, v3 = accs[3][r] * scale;
    float m = fmaxf(fmaxf(v0, v1), fmaxf(v2, v3));
    #pragma unroll
    for (int off = 8; off; off >>= 1) m = fmaxf(m, __shfl_xor(m, off));
    float e0 = __expf(v0 - m), e1 = __expf(v1 - m);
    float e2 = __expf(v2 - m), e3 = __expf(v3 - m);
    float s = e0 + e1 + e2 + e3;
    #pragma unroll
    for (int off = 8; off; off >>= 1) s += __shfl_xor(s, off);
    float inv = 1.f / s;
    int q = wave * 16 + cr + r;
    Ps[q][0 * 16 + cc] = __bfloat16_as_ushort(__float2bfloat16(e0 * inv));
    Ps[q][1 * 16 + cc] = __bfloat16_as_ushort(__float2bfloat16(e1 * inv));
    Ps[q][2 * 16 + cc] = __bfloat16_as_ushort(__float2bfloat16(e2 * inv));
    Ps[q][3 * 16 + cc] = __bfloat16_as_ushort(__float2bfloat16(e3 * inv));
  }
  __syncthreads();
  // PV: O[16w..][192] = P(16x64) @ V(64x192); B = Vt rows (dim, key)
  f32x4 acco[12] = {};
  #pragma unroll
  for (int kk = 0; kk < 2; ++kk) {
    short8 ap = *(const short8*)&Ps[wave * 16 + fr][kk * 32 + fk];
    #pragma unroll
    for (int j = 0; j < 12; ++j) {
      short8 bv = *(const short8*)&Vt[j * 16 + fr][kk * 32 + fk];
      acco[j] = __builtin_amdgcn_mfma_f32_16x16x32_bf16(ap, bv, acco[j], 0, 0, 0);
    }
  }
  bf16* ob = o + (size_t)(b * 64) * 768 + h * 192;
  #pragma unroll
  for (int j = 0; j < 12; ++j) {
    int d = j * 16 + cc;
    #pragma unroll
    for (int r = 0; r < 4; ++r) {
      int q = wave * 16 + cr + r;
      ob[(size_t)q * 768 + d] = __float2bfloat16(acco[j][r]);
    }
  }
}

// ---------------- fc2: one wave per (m,n), shuffle-reduce dot ----------------
__global__ __launch_bounds__(256) void fc2_wave(
    const bf16* __restrict__ A, const float* __restrict__ Bw,
    const float* __restrict__ bias, float* __restrict__ C, int K) {
  int m = blockIdx.x;
  int n = threadIdx.x >> 6;
  int lane = threadIdx.x & 63;
  const bf16* a = A + (size_t)m * K;
  const float* bb = Bw + (size_t)n * K;
  float acc = 0.f;
  for (int k = lane; k < K; k += 64)
    acc += __bfloat162float(a[k]) * bb[k];
  for (int off = 32; off; off >>= 1) acc += __shfl_xor(acc, off);
  if (lane == 0) C[m * 4 + n] = acc + bias[n];
}

// ---------------- transform params + translate output ----------------
__global__ __launch_bounds__(64) void params_k(
    const float* __restrict__ tp, float* __restrict__ par, float* __restrict__ trans_out) {
  int m = blockIdx.x * 64 + threadIdx.x;
  if (m >= 2048) return;
  float t0 = tp[m * 4 + 0], t1 = tp[m * 4 + 1], t2 = tp[m * 4 + 2], t3 = tp[m * 4 + 3];
  float trx = tanhf(t0), tryy = tanhf(t1);
  float s = (1.f / (1.f + expf(-t2))) * 0.3f;
  float rot = tanhf(t3) * PI_F;
  float c = cosf(rot), sn = sinf(rot);
  float x_ext = fminf(s * fabsf(c) + s * fabsf(sn), 1.f);
  float y_ext = fminf(s * fabsf(sn) + s * fabsf(c), 1.f);
  float tx = trx * (1.f - x_ext);
  float ty = tryy * (1.f - y_ext);
  par[m * 8 + 0] = s * c;
  par[m * 8 + 1] = -s * sn;
  par[m * 8 + 2] = s * sn;
  par[m * 8 + 3] = s * c;
  par[m * 8 + 4] = tx;
  par[m * 8 + 5] = ty;
  trans_out[m * 2 + 0] = tx;
  trans_out[m * 2 + 1] = ty;
}

// ---------------- bilinear grid sample (fp32 x) ----------------
__global__ __launch_bounds__(256) void sample_k(
    const float* __restrict__ x, const float* __restrict__ par, float* __restrict__ out) {
  int tid = blockIdx.x * 256 + threadIdx.x;
  if (tid >= 32 * 64 * 3 * 256) return;
  int pj = tid & 15, pi = (tid >> 4) & 15;
  int c = (tid >> 8) % 3;
  int bp = tid / 768;
  int b = bp >> 6;
  const float* pp = par + bp * 8;
  float ta = pp[0], tb = pp[1], tc = pp[2], td = pp[3], tx = pp[4], ty = pp[5];
  float bj = (2.f * pj + 1.f) / 16.f - 1.f;
  float bi = (2.f * pi + 1.f) / 16.f - 1.f;
  float gx = ta * bj + tb * bi + tx;
  float gy = tc * bj + td * bi + ty;
  float xs = ((gx + 1.f) * 128.f - 1.f) * 0.5f;
  float ys = ((gy + 1.f) * 128.f - 1.f) * 0.5f;
  float x0f = floorf(xs), y0f = floorf(ys);
  float wx = xs - x0f, wy = ys - y0f;
  int x0 = (int)x0f, y0 = (int)y0f, x1 = x0 + 1, y1 = y0 + 1;
  const float* img = x + ((size_t)b * 3 + c) * 16384;
  auto g = [&](int yi, int xi) -> float {
    bool v = (xi >= 0) && (xi < 128) && (yi >= 0) && (yi < 128);
    int yc = yi < 0 ? 0 : (yi > 127 ? 127 : yi);
    int xc = xi < 0 ? 0 : (xi > 127 ? 127 : xi);
    float val = img[yc * 128 + xc];
    return v ? val : 0.f;
  };
  float v00 = g(y0, x0), v01 = g(y0, x1), v10 = g(y1, x0), v11 = g(y1, x1);
  out[tid] = v00 * (1.f - wx) * (1.f - wy) + v01 * wx * (1.f - wy) +
             v10 * (1.f - wx) * wy + v11 * wx * wy;
}

extern "C" void kernel_launch(void* const* d_in, const int* in_sizes, int n_in,
                              void* d_out, int out_size, void* d_ws, size_t ws_size,
                              hipStream_t stream) {
  const float* x        = (const float*)d_in[0];
  const float* conv1_w  = (const float*)d_in[1];
  const float* conv1_b  = (const float*)d_in[2];
  const float* a1_in_w  = (const float*)d_in[3];
  const float* a1_in_b  = (const float*)d_in[4];
  const float* a1_qkv_w = (const float*)d_in[5];
  const float* a1_qkv_b = (const float*)d_in[6];
  const float* a1_out_w = (const float*)d_in[7];
  const float* a1_out_b = (const float*)d_in[8];
  const float* a1_proj_w = (const float*)d_in[9];
  const float* a1_proj_b = (const float*)d_in[10];
  const float* conv2_w  = (const float*)d_in[11];
  const float* conv2_b  = (const float*)d_in[12];
  const float* a2_in_w  = (const float*)d_in[13];
  const float* a2_in_b  = (const float*)d_in[14];
  const float* a2_qkv_w = (const float*)d_in[15];
  const float* a2_qkv_b = (const float*)d_in[16];
  const float* a2_out_w = (const float*)d_in[17];
  const float* a2_out_b = (const float*)d_in[18];
  const float* a2_proj_w = (const float*)d_in[19];
  const float* a2_proj_b = (const float*)d_in[20];
  const float* fc1_w    = (const float*)d_in[21];
  const float* fc1_b    = (const float*)d_in[22];
  const float* fc2_w    = (const float*)d_in[23];
  const float* fc2_b    = (const float*)d_in[24];
  float* out = (float*)d_out;

  char* ws = (char*)d_ws;
  bf16*  f1   = (bf16*)(ws + 0);            // conv1 out / proj1 out (y1)
  bf16*  y1   = f1;
  bf16*  f3   = (bf16*)(ws + 0);            // conv2 out (y1 dead)
  bf16*  h1   = (bf16*)(ws + 33554432);
  float* part = (float*)(ws + 83886080);    // split-K partials (50 MB)
  bf16*  xp   = (bf16*)(ws + 83886080);     // padded CL pool out
  bf16*  t    = (bf16*)(ws + 134217728);
  bf16*  qkv  = (bf16*)(ws + 137363456);    // bf16 now (9.4 MB)
  bf16*  o    = (bf16*)(ws + 158334976);
  bf16*  ao   = (bf16*)(ws + 161480704);
  bf16*  y2   = (bf16*)(ws + 164626432);    // also hosts Wq/Wo before proj2 writes it
  float* tp   = (float*)(ws + 181403648);
  float* par  = (float*)(ws + 181436416);
  bf16*  W    = (bf16*)(ws + 181501952);    // 25.2 MB weight scratch (reused)
  bf16*  wcl  = W;                          // conv2 weights [tap][oc][ic]
  bf16*  Wq   = (bf16*)(ws + 164626432);            // qkv_w bf16 (3.54 MB), in y2 region
  bf16*  Wo   = (bf16*)(ws + 164626432 + 3538944);  // out_w bf16 (1.18 MB)

  const unsigned short* Wu = (const unsigned short*)W;
  const unsigned short* Wqu = (const unsigned short*)Wq;
  const unsigned short* Wou = (const unsigned short*)Wo;
  const float scale = 0.07216878364870323f; // 1/sqrt(192)

  const int n_in1 = 768 * 16384 / 4, n_qkv = 2304 * 768 / 4, n_out = 768 * 768 / 4;
  const int n_in2 = 768 * 4096 / 4;
  const int n_proj1 = 16384 * 768 / 4, n_proj2 = 4096 * 768 / 4, n_fc1 = 2048 * 4096 / 4;

  conv3x3_relu_c3_fast<<<dim3(64, 32), 256, 0, stream>>>(x, conv1_w, conv1_b, f1);
  cvt3_k<<<(n_in1 + n_qkv + n_out + 255) / 256, 256, 0, stream>>>(
      a1_in_w, W, n_in1, a1_qkv_w, Wq, n_qkv, a1_out_w, Wo, n_out);
  gemm_bf16<0><<<dim3(96, 1, 8), 256, 0, stream>>>((const unsigned short*)f1, Wu, nullptr, part, 2048, 768, 16384, 2048);
  reduce_bias_k<<<1536, 256, 0, stream>>>(part, a1_in_b, t, 2048 * 768, 768, 8, 0);
  gemm_bf16<2><<<dim3(288, 1, 1), 256, 0, stream>>>((const unsigned short*)t, Wqu, a1_qkv_b, qkv, 2048, 2304, 768, 768);
  attn_fused<<<128, 256, 0, stream>>>(qkv, o, scale);
  gemm_bf16<0><<<dim3(96, 1, 3), 256, 0, stream>>>((const unsigned short*)o, Wou, nullptr, part, 2048, 768, 768, 256);
  reduce_bias_k<<<1536, 256, 0, stream>>>(part, a1_out_b, ao, 2048 * 768, 768, 3, 0);
  cvt3_k<<<(n_proj1 + 255) / 256, 256, 0, stream>>>(
      a1_proj_w, W, n_proj1, nullptr, nullptr, 0, nullptr, nullptr, 0);
  gemm_bf16<2><<<dim3(2048, 1, 1), 256, 0, stream>>>((const unsigned short*)ao, Wu, a1_proj_b, y1, 2048, 16384, 768, 768);
  cvt_wcl_k<<<144, 256, 0, stream>>>(conv2_w, wcl);
  maxpool_cl<<<dim3(1089, 32), 256, 0, stream>>>(y1, xp);
  conv2_mfma<<<dim3(32, 32), 256, 0, stream>>>(xp, wcl, conv2_b, f3);
  cvt3_k<<<(n_in2 + n_qkv + n_out + 255) / 256, 256, 0, stream>>>(
      a2_in_w, W, n_in2, a2_qkv_w, Wq, n_qkv, a2_out_w, Wo, n_out);
  gemm_bf16<0><<<dim3(96, 1, 4), 256, 0, stream>>>((const unsigned short*)f3, Wu, nullptr, part, 2048, 768, 4096, 1024);
  reduce_bias_k<<<1536, 256, 0, stream>>>(part, a2_in_b, t, 2048 * 768, 768, 4, 0);
  gemm_bf16<2><<<dim3(288, 1, 1), 256, 0, stream>>>((const unsigned short*)t, Wqu, a2_qkv_b, qkv, 2048, 2304, 768, 768);
  attn_fused<<<128, 256, 0, stream>>>(qkv, o, scale);
  gemm_bf16<0><<<dim3(96, 1, 3), 256, 0, stream>>>((const unsigned short*)o, Wou, nullptr, part, 2048, 768, 768, 256);
  reduce_bias_k<<<1536, 256, 0, stream>>>(part, a2_out_b, ao, 2048 * 768, 768, 3, 0);
  cvt3_k<<<(n_proj2 + 255) / 256, 256, 0, stream>>>(
      a2_proj_w, W, n_proj2, nullptr, nullptr, 0, nullptr, nullptr, 0);
  gemm_bf16<2><<<dim3(512, 1, 1), 256, 0, stream>>>((const unsigned short*)ao, Wu, a2_proj_b, y2, 2048, 4096, 768, 768);
  cvt3_k<<<(n_fc1 + 255) / 256, 256, 0, stream>>>(
      fc1_w, W, n_fc1, nullptr, nullptr, 0, nullptr, nullptr, 0);
  gemm_bf16<0><<<dim3(256, 1, 2), 256, 0, stream>>>((const unsigned short*)y2, Wu, nullptr, part, 2048, 2048, 4096, 2048);
  reduce_bias_k<<<4096, 256, 0, stream>>>(part, fc1_b, h1, 2048 * 2048, 2048, 2, 1);
  fc2_wave<<<2048, 256, 0, stream>>>(h1, fc2_w, fc2_b, tp, 2048);
  params_k<<<32, 64, 0, stream>>>(tp, par, out + 1572864);
  sample_k<<<6144, 256, 0, stream>>>(x, par, out);
}